// Round 7
// baseline (590.431 us; speedup 1.0000x reference)
//
#include <hip/hip_runtime.h>
#include <hip/hip_bf16.h>
#include <math.h>

#define NREL 20
#define NN   4096
#define NE   16384
#define DF   512      // flattened feature width (H*HID)
#define NHD  4        // GAT heads
#define DHH  128      // per-head dim
#define NB   16       // graphs
#define NS   256      // nodes per graph

typedef __attribute__((ext_vector_type(8))) __bf16 bf16x8;
typedef __attribute__((ext_vector_type(4))) float f32x4;
typedef __attribute__((ext_vector_type(2))) float f32x2;

struct f8 { unsigned char b; };                         // fp8 e4m3 (OCP) storage

__device__ inline float bf2f(unsigned short u) {
    union { float f; unsigned int i; } c; c.i = ((unsigned int)u) << 16; return c.f;
}
__device__ inline unsigned short f2bu(float f) {
    union { __hip_bfloat16 b; unsigned short u; } c; c.b = __float2bfloat16(f); return c.u;
}
__device__ inline void storeOut(float* p, float v) { *p = v; }
__device__ inline void storeOut(__hip_bfloat16* p, float v) { *p = __float2bfloat16(v); }

__device__ inline void load_lds16(const __hip_bfloat16* g, __hip_bfloat16* l) {
    __builtin_amdgcn_global_load_lds(
        (const __attribute__((address_space(1))) unsigned int*)(const void*)g,
        (__attribute__((address_space(3))) unsigned int*)(void*)l, 16, 0, 0);
}

// K-chunk swizzle: within each 64-elem K-group, XOR the 8-elem chunk id
// (bits [5:3] of k) with (row&7). Producer-side for all GEMM A/B operands.
__device__ inline int kswz(int f, int row) { return f ^ (((row) & 7) << 3); }

// ---------------- prep: zero cnt/imp, cast+swizzle feat, bias sums ----------
__global__ __launch_bounds__(256) void prep_kernel(
    const float* __restrict__ feat, unsigned short* __restrict__ featbf,
    const float* __restrict__ b1, const float* __restrict__ b2,
    const float* __restrict__ bk, const float* __restrict__ bv,
    float* __restrict__ bsum1, float* __restrict__ bsum2,
    float* __restrict__ bkv, int* __restrict__ cnt, float* __restrict__ imp)
{
    int blk = blockIdx.x, t = threadIdx.x;
    if (blk < 1024) {
        int idx = blk * 256 + t;                        // chunk id < NN*DF/8
        int row = idx >> 6;                             // 64 chunks per row
        int f = (idx & 63) * 8;
        int fs = kswz(f, row);
        const float4* ip = (const float4*)&feat[(size_t)row * DF + f];
        float4 v0 = ip[0], v1 = ip[1];
        union { unsigned short u[8]; uint4 q; } o;
        o.u[0] = f2bu(v0.x); o.u[1] = f2bu(v0.y); o.u[2] = f2bu(v0.z); o.u[3] = f2bu(v0.w);
        o.u[4] = f2bu(v1.x); o.u[5] = f2bu(v1.y); o.u[6] = f2bu(v1.z); o.u[7] = f2bu(v1.w);
        *(uint4*)(featbf + (size_t)row * DF + fs) = o.q;
    } else if (blk == 1024) {
        #pragma unroll
        for (int rep = 0; rep < 2; ++rep) {
            int f = t + rep * 256;
            float s1 = 0.f, s2 = 0.f;
            #pragma unroll
            for (int r = 0; r < NREL; ++r) { s1 += b1[r * DF + f]; s2 += b2[r * DF + f]; }
            bsum1[f] = s1; bsum2[f] = s2;
        }
        for (int i = t; i < NN; i += 256) imp[i] = 0.f;
    } else if (blk == 1025) {
        #pragma unroll
        for (int j = 0; j < 4; ++j) {
            int f = t + j * 256;
            bkv[f] = (f < DF) ? bk[f] : bv[f - DF];
        }
    } else {
        int idx = (blk - 1026) * 256 + t;               // < NREL*NN
        cnt[idx] = 0;
    }
}

// ---------------- CSR build ----------------
__global__ void count_kernel(const int* __restrict__ dst, int* __restrict__ cnt) {
    int idx = blockIdx.x * 256 + threadIdx.x;          // < NREL*NE
    int r = idx / NE;
    atomicAdd(&cnt[r * NN + dst[idx]], 1);
}

__global__ void scan_kernel(const int* __restrict__ cnt, int* __restrict__ rowptr,
                            int* __restrict__ woff, int* __restrict__ rowptr2,
                            int* __restrict__ croff) {
    int r = blockIdx.x;
    int t = threadIdx.x;                                // 1024 threads
    __shared__ int sums[1024];
    int v[4]; int local = 0;
    if (r < NREL) {
        #pragma unroll
        for (int j = 0; j < 4; ++j) { v[j] = cnt[r * NN + t * 4 + j]; local += v[j]; }
    } else {
        #pragma unroll
        for (int j = 0; j < 4; ++j) {
            int s = 0;
            for (int rel = 0; rel < NREL; ++rel) {
                croff[rel * NN + t * 4 + j] = s;
                s += cnt[rel * NN + t * 4 + j];
            }
            v[j] = s; local += s;
        }
    }
    sums[t] = local;
    __syncthreads();
    for (int off = 1; off < 1024; off <<= 1) {
        int x = (t >= off) ? sums[t - off] : 0;
        __syncthreads();
        sums[t] += x;
        __syncthreads();
    }
    int run = (t == 0) ? 0 : sums[t - 1];               // exclusive prefix
    if (r < NREL) {
        #pragma unroll
        for (int j = 0; j < 4; ++j) {
            rowptr[r * (NN + 1) + t * 4 + j] = run;
            woff[r * NN + t * 4 + j] = run;
            run += v[j];
        }
        if (t == 1023) rowptr[r * (NN + 1) + NN] = run;
    } else {
        #pragma unroll
        for (int j = 0; j < 4; ++j) { rowptr2[t * 4 + j] = run; run += v[j]; }
        if (t == 1023) rowptr2[NN] = run;
    }
}

__global__ void fill_kernel(const int* __restrict__ dst, const int* __restrict__ src,
                            int* __restrict__ woff, int* __restrict__ srcCSR,
                            int* __restrict__ eidCSR) {
    int idx = blockIdx.x * 256 + threadIdx.x;
    int r = idx / NE; int e = idx % NE;
    int pos = atomicAdd(&woff[r * NN + dst[idx]], 1);
    srcCSR[r * NE + pos] = src[idx];
    eidCSR[r * NE + pos] = e;
}

// ---------------- W[r][K][N] fp32 -> Wt[r][N][K] bf16 (transpose+cast+swz) --
__global__ __launch_bounds__(256) void transw_kernel(
    const float* __restrict__ W, __hip_bfloat16* __restrict__ Wt, int K, int N)
{
    int r = blockIdx.z;
    __shared__ float t[32][33];
    int k0 = blockIdx.x * 32, n0 = blockIdx.y * 32;
    int tx = threadIdx.x % 32, ty = threadIdx.x / 32;   // 8 rows
    #pragma unroll
    for (int kk = ty; kk < 32; kk += 8)
        t[kk][tx] = W[((size_t)r * K + k0 + kk) * N + n0 + tx];
    __syncthreads();
    #pragma unroll
    for (int nn = ty; nn < 32; nn += 8) {
        int row = n0 + nn;
        Wt[((size_t)r * N + row) * K + kswz(k0 + tx, row)] = __float2bfloat16(t[tx][nn]);
    }
}

// merged W1+W2+Wk+Wv transpose: z in [0, 2*NREL+2)
__global__ __launch_bounds__(256) void transw2_kernel(
    const float* __restrict__ W1, const float* __restrict__ W2,
    const float* __restrict__ Wk, const float* __restrict__ Wv,
    __hip_bfloat16* __restrict__ Wt1, __hip_bfloat16* __restrict__ Wt2,
    __hip_bfloat16* __restrict__ WtKV)
{
    int z = blockIdx.z;
    const float* Wsrc; __hip_bfloat16* Wdst;
    if (z < NREL)           { Wsrc = W1 + (size_t)z * DF * DF;          Wdst = Wt1 + (size_t)z * DF * DF; }
    else if (z < 2 * NREL)  { Wsrc = W2 + (size_t)(z - NREL) * DF * DF; Wdst = Wt2 + (size_t)(z - NREL) * DF * DF; }
    else if (z == 2 * NREL) { Wsrc = Wk;                                Wdst = WtKV; }
    else                    { Wsrc = Wv;                                Wdst = WtKV + (size_t)DF * DF; }
    __shared__ float t[32][33];
    int k0 = blockIdx.x * 32, n0 = blockIdx.y * 32;
    int tx = threadIdx.x % 32, ty = threadIdx.x / 32;
    #pragma unroll
    for (int kk = ty; kk < 32; kk += 8)
        t[kk][tx] = Wsrc[(size_t)(k0 + kk) * DF + n0 + tx];
    __syncthreads();
    #pragma unroll
    for (int nn = ty; nn < 32; nn += 8) {
        int row = n0 + nn;
        Wdst[(size_t)row * DF + kswz(k0 + tx, row)] = __float2bfloat16(t[tx][nn]);
    }
}

// ---------------- 256x128 triple-buffered Z-GEMM (bf16 MFMA -> fp8 + el/er) -
// 16 waves (4M x 4N), wave tile 64x32 (acc[4][2] = 32 AGPR, ~90 regs/wave ->
// 4 waves/SIMD). Grid = 4 x 16 x 20 = 1280 = exactly 5 x 256 CUs (no tail).
// LDS: As[3][256][64] (96 KB) + Bs[3][128][64] (48 KB) = 144 KB triple-buffer.
// Per K-tile (ONE barrier, counted vmcnt(3) never drained mid-loop):
//   stage kt+2 -> buf[(kt+2)%3]   (readers of that buf finished before the
//                                  end-of-(kt-1) barrier we just crossed)
//   read ks0 (6 ds_read) ; lgkm0 ; 8 MFMA
//   read ks1 (6)         ; lgkm0 ; 8 MFMA
//   vmcnt(3) (waits kt+1's stage, leaves kt+2 in flight) ; barrier
// Accumulation order per acc[i][j]: ks0 then ks1, kt ascending — identical to
// all previous rounds -> bitwise-same accumulators. el/er now reduce in 4
// strips of 32 cols (was 2x64): fp reassociation only, ~1e-6.
__global__ __launch_bounds__(1024) void zgemm3(
    const __hip_bfloat16* __restrict__ A,
    const __hip_bfloat16* __restrict__ BtAll,
    unsigned char* __restrict__ Zall,
    const float* __restrict__ al, const float* __restrict__ ar,
    float* __restrict__ el, float* __restrict__ er)
{
    const int r = blockIdx.z;
    const __hip_bfloat16* Bt = BtAll + (size_t)r * DF * DF;
    unsigned char* Z = Zall + (size_t)r * NN * DF;
    const int rowBase = blockIdx.y * 256;
    const int colBase = blockIdx.x * 128;
    __shared__ __hip_bfloat16 As[3][256][64];           // 96 KB
    __shared__ __hip_bfloat16 Bs[3][128][64];           // 48 KB
    const int tid = threadIdx.x;
    const int w = tid >> 6, l = tid & 63;
    const int wr = w >> 2, wc = w & 3;                  // 4 x 4 wave grid
    const int m15 = l & 15, q = l >> 4;
    const int swr = m15 & 7;

    // staging: A covers 256 rows via 2 loads (rows tid>>3 and +128);
    // B covers 128 rows via 1 load. Linear LDS dest, pre-swizzled global src.
    const __hip_bfloat16* Ag = A + (size_t)(rowBase + (tid >> 3)) * DF + (tid & 7) * 8;
    const __hip_bfloat16* Bg = Bt + (size_t)(colBase + (tid >> 3)) * DF + (tid & 7) * 8;
    __hip_bfloat16* AsT = &As[0][0][0] + tid * 8;
    __hip_bfloat16* BsT = &Bs[0][0][0] + tid * 8;

#define STAGE_A(buf, kt) do { \
        const __hip_bfloat16* s_ = Ag + (kt) * 64; \
        __hip_bfloat16* d_ = AsT + (buf) * 16384; \
        load_lds16(s_, d_); \
        load_lds16(s_ + (size_t)128 * DF, d_ + 8192); } while (0)
#define STAGE_B(buf, kt) do { \
        load_lds16(Bg + (kt) * 64, BsT + (buf) * 8192); } while (0)

    f32x4 acc[4][2];
    #pragma unroll
    for (int i = 0; i < 4; ++i)
        #pragma unroll
        for (int j = 0; j < 2; ++j) acc[i][j] = (f32x4){0.f, 0.f, 0.f, 0.f};

    const int NT = DF / 64;                             // 8 K-tiles
    // prologue: kt0 -> b0, kt1 -> b1 (6 loads); wait kt0's 3, leave kt1's 3
    STAGE_A(0, 0); STAGE_B(0, 0);
    STAGE_A(1, 1); STAGE_B(1, 1);
    asm volatile("s_waitcnt vmcnt(3)" ::: "memory");
    __builtin_amdgcn_s_barrier();
    __builtin_amdgcn_sched_barrier(0);

    bf16x8 a[4], b[2];
    #pragma unroll
    for (int kt = 0; kt < NT; ++kt) {
        const int buf = kt % 3;
        // stage kt+2 into buf[(kt+2)%3]; its readers (tile kt-1) finished
        // before the barrier we just crossed.
        if (kt + 2 < NT) {
            const int sb = (kt + 2) % 3;
            STAGE_A(sb, kt + 2); STAGE_B(sb, kt + 2);
        }
        __builtin_amdgcn_sched_barrier(0);
        // ---- ks0 fragment reads ----
        #pragma unroll
        for (int i = 0; i < 4; ++i)
            a[i] = *(const bf16x8*)&As[buf][wr * 64 + i * 16 + m15][(q ^ swr) * 8];
        #pragma unroll
        for (int j = 0; j < 2; ++j)
            b[j] = *(const bf16x8*)&Bs[buf][wc * 32 + j * 16 + m15][(q ^ swr) * 8];
        asm volatile("s_waitcnt lgkmcnt(0)" ::: "memory");
        __builtin_amdgcn_sched_barrier(0);
        __builtin_amdgcn_s_setprio(1);
        #pragma unroll
        for (int i = 0; i < 4; ++i)
            #pragma unroll
            for (int j = 0; j < 2; ++j)
                acc[i][j] = __builtin_amdgcn_mfma_f32_16x16x32_bf16(a[i], b[j], acc[i][j], 0, 0, 0);
        __builtin_amdgcn_s_setprio(0);
        // ---- ks1 fragment reads ----
        #pragma unroll
        for (int i = 0; i < 4; ++i)
            a[i] = *(const bf16x8*)&As[buf][wr * 64 + i * 16 + m15][((4 + q) ^ swr) * 8];
        #pragma unroll
        for (int j = 0; j < 2; ++j)
            b[j] = *(const bf16x8*)&Bs[buf][wc * 32 + j * 16 + m15][((4 + q) ^ swr) * 8];
        asm volatile("s_waitcnt lgkmcnt(0)" ::: "memory");
        __builtin_amdgcn_sched_barrier(0);
        __builtin_amdgcn_s_setprio(1);
        #pragma unroll
        for (int i = 0; i < 4; ++i)
            #pragma unroll
            for (int j = 0; j < 2; ++j)
                acc[i][j] = __builtin_amdgcn_mfma_f32_16x16x32_bf16(a[i], b[j], acc[i][j], 0, 0, 0);
        __builtin_amdgcn_s_setprio(0);
        // counted wait: kt+1's 3 loads (issued last tile) must be in LDS;
        // kt+2's 3 (issued this tile) stay in flight across the barrier.
        if (kt + 2 < NT)      { asm volatile("s_waitcnt vmcnt(3)" ::: "memory"); }
        else if (kt + 1 < NT) { asm volatile("s_waitcnt vmcnt(0)" ::: "memory"); }
        __builtin_amdgcn_s_barrier();
        __builtin_amdgcn_sched_barrier(0);
    }
#undef STAGE_A
#undef STAGE_B

    // ---- epilogue: fp8 pack through LDS (As, 32 KB of 96), coalesced store -
    unsigned char* cbuf = (unsigned char*)&As[0][0][0];
    #pragma unroll
    for (int i = 0; i < 4; ++i)
        #pragma unroll
        for (int j = 0; j < 2; ++j) {
            int colL = wc * 32 + j * 16 + m15;
            #pragma unroll
            for (int reg = 0; reg < 4; ++reg) {
                int rowL = wr * 64 + i * 16 + q * 4 + reg;
                unsigned int pk = __builtin_amdgcn_cvt_pk_fp8_f32(
                    acc[i][j][reg], acc[i][j][reg], 0, false);
                cbuf[rowL * 128 + colL] = (unsigned char)(pk & 0xFF);
            }
        }
    __syncthreads();
    {
        int rowL = tid >> 2, colL = (tid & 3) * 32;     // 32 B per thread
        const uint4* src = (const uint4*)&cbuf[rowL * 128 + colL];
        uint4* dst = (uint4*)(Z + (size_t)(rowBase + rowL) * DF + colBase + colL);
        dst[0] = src[0]; dst[1] = src[1];
    }

    // ---- el/er fuse: block covers exactly ONE head (128 cols) -------------
    float alv[2], arv[2];
    #pragma unroll
    for (int j = 0; j < 2; ++j) {
        int col = colBase + wc * 32 + j * 16 + m15;
        alv[j] = al[r * DF + col];
        arv[j] = ar[r * DF + col];
    }
    float pe[4][4], pr[4][4];
    #pragma unroll
    for (int i = 0; i < 4; ++i)
        #pragma unroll
        for (int reg = 0; reg < 4; ++reg) {
            float se = 0.f, sr = 0.f;
            #pragma unroll
            for (int j = 0; j < 2; ++j) {
                se += acc[i][j][reg] * alv[j];
                sr += acc[i][j][reg] * arv[j];
            }
            pe[i][reg] = se; pr[i][reg] = sr;
        }
    #pragma unroll
    for (int off = 1; off < 16; off <<= 1)
        #pragma unroll
        for (int i = 0; i < 4; ++i)
            #pragma unroll
            for (int reg = 0; reg < 4; ++reg) {
                pe[i][reg] += __shfl_xor(pe[i][reg], off);
                pr[i][reg] += __shfl_xor(pr[i][reg], off);
            }
    float* eP = (float*)&Bs[0][0][0];                   // [256 rows][4 strips]
    float* rP = eP + 1024;
    if (m15 == 0) {
        #pragma unroll
        for (int i = 0; i < 4; ++i)
            #pragma unroll
            for (int reg = 0; reg < 4; ++reg) {
                int rowL = wr * 64 + i * 16 + q * 4 + reg;
                eP[rowL * 4 + wc] = pe[i][reg];
                rP[rowL * 4 + wc] = pr[i][reg];
            }
    }
    __syncthreads();
    if (tid < 256) {
        int head = colBase >> 7;
        size_t idx = ((size_t)r * NN + rowBase + tid) * NHD + head;
        el[idx] = (eP[tid * 4] + eP[tid * 4 + 1]) + (eP[tid * 4 + 2] + eP[tid * 4 + 3]);
        er[idx] = (rP[tid * 4] + rP[tid * 4 + 1]) + (rP[tid * 4 + 2] + rP[tid * 4 + 3]);
    }
}

// ---------------- bf16 MFMA GEMM: C[r] = A @ Bt[r]^T (+bias, opt relu) ------
// 128^2 tile, kept for KV projection and the split-K classifier GEMM.
template <typename OutT, bool RELU, bool FUSE, bool SPLITK = false>
__global__ __launch_bounds__(256) void mfma_gemm(
    const __hip_bfloat16* __restrict__ A,
    const __hip_bfloat16* __restrict__ BtAll,
    const float* __restrict__ bias, int biasStride,
    OutT* __restrict__ Call, int M, int N, int K, int lda,
    const float* __restrict__ al, const float* __restrict__ ar,
    float* __restrict__ el, float* __restrict__ er)
{
    int r = blockIdx.z;
    const __hip_bfloat16* Bt;
    int koff;
    if (SPLITK) { Bt = BtAll;                         koff = r * K; }
    else        { Bt = BtAll + (size_t)r * N * lda;   koff = 0; }
    OutT* C = Call + (size_t)r * M * N;
    const int rowBase = blockIdx.y * 128;
    const int colBase = blockIdx.x * 128;
    __shared__ __hip_bfloat16 As[128 * 64];
    __shared__ __hip_bfloat16 Bs[128 * 64];
    const int tid = threadIdx.x;
    const int w = tid >> 6, l = tid & 63;
    const int wr = w >> 1, wc = w & 1;
    const int m15 = l & 15, q = l >> 4;
    const int sRow = tid >> 3;                          // 0..31 (call adds 32*c)
    const int sChk = tid & 7;
    const __hip_bfloat16* Ag = A + (size_t)(rowBase + sRow) * lda + koff + sChk * 8;
    const __hip_bfloat16* Bg = Bt + (size_t)(colBase + sRow) * lda + koff + sChk * 8;
    __hip_bfloat16* Asl = As + tid * 8;
    __hip_bfloat16* Bsl = Bs + tid * 8;
    const int swr = m15 & 7;                            // read-side swizzle

    f32x4 acc[4][4];
    #pragma unroll
    for (int i = 0; i < 4; ++i)
        #pragma unroll
        for (int j = 0; j < 4; ++j) acc[i][j] = (f32x4){0.f, 0.f, 0.f, 0.f};

    for (int k0 = 0; k0 < K; k0 += 64) {
        #pragma unroll
        for (int c = 0; c < 4; ++c) {
            load_lds16(Ag + (size_t)c * 32 * lda + k0, Asl + c * 2048);
            load_lds16(Bg + (size_t)c * 32 * lda + k0, Bsl + c * 2048);
        }
        __syncthreads();
        #pragma unroll
        for (int g = 0; g < 2; ++g) {
            bf16x8 a[4], b[4];
            #pragma unroll
            for (int i = 0; i < 4; ++i)
                a[i] = *(const bf16x8*)&As[(wr * 64 + i * 16 + m15) * 64 + ((g * 4 + q) ^ swr) * 8];
            #pragma unroll
            for (int j = 0; j < 4; ++j)
                b[j] = *(const bf16x8*)&Bs[(wc * 64 + j * 16 + m15) * 64 + ((g * 4 + q) ^ swr) * 8];
            #pragma unroll
            for (int i = 0; i < 4; ++i)
                #pragma unroll
                for (int j = 0; j < 4; ++j)
                    acc[i][j] = __builtin_amdgcn_mfma_f32_16x16x32_bf16(a[i], b[j], acc[i][j], 0, 0, 0);
        }
        __syncthreads();
    }

    if constexpr (sizeof(OutT) == 1) {
        unsigned char* cbuf = (unsigned char*)As;
        #pragma unroll
        for (int i = 0; i < 4; ++i)
            #pragma unroll
            for (int j = 0; j < 4; ++j) {
                int colL = wc * 64 + j * 16 + m15;
                #pragma unroll
                for (int reg = 0; reg < 4; ++reg) {
                    int rowL = wr * 64 + i * 16 + q * 4 + reg;
                    unsigned int pk = __builtin_amdgcn_cvt_pk_fp8_f32(
                        acc[i][j][reg], acc[i][j][reg], 0, false);
                    cbuf[rowL * 128 + colL] = (unsigned char)(pk & 0xFF);
                }
            }
        __syncthreads();
        int rowL = tid >> 1, colL = (tid & 1) * 64;
        const uint4* src = (const uint4*)&cbuf[rowL * 128 + colL];
        uint4* dst = (uint4*)((unsigned char*)C + (size_t)(rowBase + rowL) * N
                              + colBase + colL);
        #pragma unroll
        for (int x = 0; x < 4; ++x) dst[x] = src[x];
    } else {
        #pragma unroll
        for (int i = 0; i < 4; ++i) {
            #pragma unroll
            for (int j = 0; j < 4; ++j) {
                int col = colBase + wc * 64 + j * 16 + m15;
                float bv = bias ? bias[r * biasStride + col] : 0.f;
                #pragma unroll
                for (int reg = 0; reg < 4; ++reg) {
                    int row = rowBase + wr * 64 + i * 16 + q * 4 + reg;
                    float v = acc[i][j][reg] + bv;
                    if (RELU) v = fmaxf(v, 0.f);
                    storeOut(&C[(size_t)row * N + col], v);
                }
            }
        }
    }

    if (FUSE) {
        float alv[4], arv[4];
        #pragma unroll
        for (int j = 0; j < 4; ++j) {
            int col = colBase + wc * 64 + j * 16 + m15;
            alv[j] = al[r * DF + col];
            arv[j] = ar[r * DF + col];
        }
        float pe[4][4], pr[4][4];
        #pragma unroll
        for (int i = 0; i < 4; ++i)
            #pragma unroll
            for (int reg = 0; reg < 4; ++reg) {
                float se = 0.f, sr = 0.f;
                #pragma unroll
                for (int j = 0; j < 4; ++j) {
                    se += acc[i][j][reg] * alv[j];
                    sr += acc[i][j][reg] * arv[j];
                }
                pe[i][reg] = se; pr[i][reg] = sr;
            }
        #pragma unroll
        for (int off = 1; off < 16; off <<= 1)
            #pragma unroll
            for (int i = 0; i < 4; ++i)
                #pragma unroll
                for (int reg = 0; reg < 4; ++reg) {
                    pe[i][reg] += __shfl_xor(pe[i][reg], off);
                    pr[i][reg] += __shfl_xor(pr[i][reg], off);
                }
        float* eP = (float*)Bs;
        float* rP = eP + 256;
        if (m15 == 0) {
            #pragma unroll
            for (int i = 0; i < 4; ++i)
                #pragma unroll
                for (int reg = 0; reg < 4; ++reg) {
                    int rowL = wr * 64 + i * 16 + q * 4 + reg;
                    eP[rowL * 2 + wc] = pe[i][reg];
                    rP[rowL * 2 + wc] = pr[i][reg];
                }
        }
        __syncthreads();
        if (tid < 128) {
            int head = colBase >> 7;
            size_t idx = ((size_t)r * NN + rowBase + tid) * NHD + head;
            el[idx] = eP[tid * 2] + eP[tid * 2 + 1];
            er[idx] = rP[tid * 2] + rP[tid * 2 + 1];
        }
    }
}

// ---------------- fp32 VALU GEMM for tiny M (q, ctx projections) ------------
template <typename OutT>
__global__ __launch_bounds__(256) void gemm_kernel(
    const float* __restrict__ A, const float* __restrict__ Bm,
    const float* __restrict__ bias, OutT* __restrict__ C,
    int M, int K, int Nn)
{
    int r = blockIdx.z;
    const float* B = Bm + (size_t)r * K * Nn;
    OutT* Cr = C + (size_t)r * M * Nn;
    int rowBase = blockIdx.y * 64;
    int colBase = blockIdx.x * 64;
    __shared__ float As[64][17];
    __shared__ float Bs[16][64];
    int tid = threadIdx.x;
    int tx = tid % 16, ty = tid / 16;
    float acc[4][4] = {};
    int aRow = tid / 4, aK4 = (tid % 4) * 4;
    int bK = tid / 16, bN4 = (tid % 16) * 4;
    for (int k0 = 0; k0 < K; k0 += 16) {
        int gRow = rowBase + aRow;
        float4 av = make_float4(0.f, 0.f, 0.f, 0.f);
        if (gRow < M) av = *(const float4*)(A + (size_t)gRow * K + k0 + aK4);
        As[aRow][aK4 + 0] = av.x; As[aRow][aK4 + 1] = av.y;
        As[aRow][aK4 + 2] = av.z; As[aRow][aK4 + 3] = av.w;
        float4 bv = *(const float4*)(B + (size_t)(k0 + bK) * Nn + colBase + bN4);
        *(float4*)&Bs[bK][bN4] = bv;
        __syncthreads();
        #pragma unroll
        for (int k = 0; k < 16; ++k) {
            float a[4], b[4];
            #pragma unroll
            for (int i = 0; i < 4; ++i) a[i] = As[ty * 4 + i][k];
            #pragma unroll
            for (int j = 0; j < 4; ++j) b[j] = Bs[k][tx * 4 + j];
            #pragma unroll
            for (int i = 0; i < 4; ++i)
                #pragma unroll
                for (int j = 0; j < 4; ++j) acc[i][j] += a[i] * b[j];
        }
        __syncthreads();
    }
    #pragma unroll
    for (int i = 0; i < 4; ++i) {
        int gRow = rowBase + ty * 4 + i;
        if (gRow >= M) continue;
        #pragma unroll
        for (int j = 0; j < 4; ++j) {
            int gCol = colBase + tx * 4 + j;
            float v = acc[i][j];
            if (bias) v += bias[gCol];
            storeOut(&Cr[(size_t)gRow * Nn + gCol], v);
        }
    }
}

// ---------------- per-(rel,node): den + alpha, pack into combined CSR -------
__global__ __launch_bounds__(256) void alpha_kernel(
    const float* __restrict__ el, const float* __restrict__ er,
    const int* __restrict__ rowptr, const int* __restrict__ rowptr2,
    const int* __restrict__ croff, const int* __restrict__ srcCSR,
    const int* __restrict__ eidCSR,
    float* __restrict__ alphaPk, int* __restrict__ srcPk,
    float* __restrict__ attn, float* __restrict__ imp)
{
    int t = blockIdx.x * 256 + threadIdx.x;             // < NREL*NN
    int r = t / NN, n = t % NN;
    int start = rowptr[r * (NN + 1) + n];
    int d = rowptr[r * (NN + 1) + n + 1] - start;
    if (d == 0) return;
    int pbase = rowptr2[n] + croff[r * NN + n];
    float4 er4 = *(const float4*)&er[((size_t)r * NN + n) * NHD];
    float4 den = make_float4(0.f, 0.f, 0.f, 0.f);
    for (int j = 0; j < d; ++j) {
        int s = srcCSR[r * NE + start + j];
        float4 el4 = *(const float4*)&el[((size_t)r * NN + s) * NHD];
        float v0 = el4.x + er4.x; v0 = v0 > 0.f ? v0 : 0.2f * v0;
        float v1 = el4.y + er4.y; v1 = v1 > 0.f ? v1 : 0.2f * v1;
        float v2 = el4.z + er4.z; v2 = v2 > 0.f ? v2 : 0.2f * v2;
        float v3 = el4.w + er4.w; v3 = v3 > 0.f ? v3 : 0.2f * v3;
        float4 e4 = make_float4(__expf(v0), __expf(v1), __expf(v2), __expf(v3));
        den.x += e4.x; den.y += e4.y; den.z += e4.z; den.w += e4.w;
        *(float4*)&alphaPk[(size_t)(pbase + j) * 4] = e4;
        srcPk[pbase + j] = r * NN + s;                  // direct Z-row index
    }
    float4 inv = make_float4(1.f / den.x, 1.f / den.y, 1.f / den.z, 1.f / den.w);
    float impLoc = 0.f;
    for (int j = 0; j < d; ++j) {
        float4 a4 = *(const float4*)&alphaPk[(size_t)(pbase + j) * 4];
        a4.x *= inv.x; a4.y *= inv.y; a4.z *= inv.z; a4.w *= inv.w;
        *(float4*)&alphaPk[(size_t)(pbase + j) * 4] = a4;
        if (attn) {
            float a = 0.25f * (a4.x + a4.y + a4.z + a4.w);
            attn[r * NE + eidCSR[r * NE + start + j]] = a;
            impLoc += a;
        }
    }
    if (attn) atomicAdd(&imp[n], impLoc);
}

// ---------------- combined aggregation: block per node, 4 waves -------------
__global__ __launch_bounds__(256) void aggc_kernel(
    const unsigned char* __restrict__ Z,
    const int* __restrict__ rowptr2, const int* __restrict__ srcPk,
    const float* __restrict__ alphaPk, const float* __restrict__ bsum,
    const float* __restrict__ hin, float* __restrict__ hout,
    __hip_bfloat16* __restrict__ hout_bf, int applyElu)
{
    int n = blockIdx.x;
    int w = threadIdx.x >> 6, lane = threadIdx.x & 63;
    int h = lane >> 4;
    int base = rowptr2[n];
    int deg = rowptr2[n + 1] - base;
    float acc[8] = {};
    if (deg > 0) {
        int i = w * 4;
        int zz[4]; float aa[4];
        #pragma unroll
        for (int j = 0; j < 4; ++j) {
            int idx = i + j; int cidx = idx < deg ? idx : deg - 1;
            zz[j] = srcPk[base + cidx];
            aa[j] = (idx < deg) ? alphaPk[(size_t)(base + cidx) * 4 + h] : 0.f;
        }
        while (i < deg) {
            int cz[4]; float ca[4];
            #pragma unroll
            for (int j = 0; j < 4; ++j) { cz[j] = zz[j]; ca[j] = aa[j]; }
            int ni = i + 16;
            #pragma unroll
            for (int j = 0; j < 4; ++j) {
                int idx = ni + j; int cidx = idx < deg ? idx : deg - 1;
                zz[j] = srcPk[base + cidx];
                aa[j] = (idx < deg) ? alphaPk[(size_t)(base + cidx) * 4 + h] : 0.f;
            }
            uint2 raw[4];
            #pragma unroll
            for (int j = 0; j < 4; ++j)
                raw[j] = *(const uint2*)&Z[(size_t)cz[j] * DF + lane * 8];
            #pragma unroll
            for (int j = 0; j < 4; ++j) {
                f32x2 f01 = __builtin_amdgcn_cvt_pk_f32_fp8((int)raw[j].x, false);
                f32x2 f23 = __builtin_amdgcn_cvt_pk_f32_fp8((int)raw[j].x, true);
                f32x2 f45 = __builtin_amdgcn_cvt_pk_f32_fp8((int)raw[j].y, false);
                f32x2 f67 = __builtin_amdgcn_cvt_pk_f32_fp8((int)raw[j].y, true);
                acc[0] += ca[j] * f01.x; acc[1] += ca[j] * f01.y;
                acc[2] += ca[j] * f23.x; acc[3] += ca[j] * f23.y;
                acc[4] += ca[j] * f45.x; acc[5] += ca[j] * f45.y;
                acc[6] += ca[j] * f67.x; acc[7] += ca[j] * f67.y;
            }
            i = ni;
        }
    }
    __shared__ float red[4][DF];
    #pragma unroll
    for (int j = 0; j < 8; ++j) red[w][lane * 8 + j] = acc[j];
    __syncthreads();
    const float invR = 1.0f / NREL;
    const int sw = (n & 7) << 3;
    int f = threadIdx.x;
    #pragma unroll
    for (int rep = 0; rep < 2; ++rep, f += 256) {
        float v = red[0][f] + red[1][f] + red[2][f] + red[3][f];
        v = (v + bsum[f]) * invR + hin[(size_t)n * DF + f];
        if (applyElu) v = v > 0.f ? v : expm1f(v);
        hout[(size_t)n * DF + f] = v;
        hout_bf[(size_t)n * DF + (f ^ sw)] = __float2bfloat16(v);   // swizzled
    }
}

// ---------------- MHA: scores, then fused softmax+context -------------------
__global__ __launch_bounds__(256) void mha_scores(
    const float* __restrict__ q, const float* __restrict__ k,
    float* __restrict__ scores)
{
    int b = blockIdx.x;
    int w = threadIdx.x >> 6, lane = threadIdx.x & 63;
    int s = blockIdx.y * 4 + w;
    const float4* qp = (const float4*)&q[(size_t)b * DF + lane * 8];
    const float4* kp = (const float4*)&k[((size_t)(b * NS + s)) * DF + lane * 8];
    float4 q0 = qp[0], q1 = qp[1];
    float4 k0 = kp[0], k1 = kp[1];
    float p = q0.x * k0.x + q0.y * k0.y + q0.z * k0.z + q0.w * k0.w
            + q1.x * k1.x + q1.y * k1.y + q1.z * k1.z + q1.w * k1.w;
    #pragma unroll
    for (int off = 1; off < 16; off <<= 1) p += __shfl_xor(p, off);
    if ((lane & 15) == 0) {
        int h = lane >> 4;
        scores[((size_t)(b * NHD + h)) * NS + s] = p * 0.08838834764831845f;
    }
}

// softmax folded in (was a separate mha_soft launch)
__global__ __launch_bounds__(256) void mha_ctx(
    const float* __restrict__ scores, const float* __restrict__ v,
    float* __restrict__ ctx)
{
    int b = blockIdx.x, h = blockIdx.y;
    int t = threadIdx.x;
    int lane = t & 63, w = t >> 6;
    __shared__ float a_s[NS];
    __shared__ float wred[8];
    float sv = scores[((size_t)(b * NHD + h)) * NS + t];
    float mx = sv;
    #pragma unroll
    for (int off = 1; off < 64; off <<= 1) mx = fmaxf(mx, __shfl_xor(mx, off));
    if (lane == 0) wred[w] = mx;
    __syncthreads();
    mx = fmaxf(fmaxf(wred[0], wred[1]), fmaxf(wred[2], wred[3]));
    float e = __expf(sv - mx);
    float sum = e;
    #pragma unroll
    for (int off = 1; off < 64; off <<= 1) sum += __shfl_xor(sum, off);
    if (lane == 0) wred[4 + w] = sum;
    __syncthreads();
    sum = wred[4] + wred[5] + wred[6] + wred[7];
    a_s[t] = e * (1.0f / sum);
    __syncthreads();
    int d = t & 127, half = t >> 7;
    float acc = 0.f;
    const float* vp = &v[((size_t)(b * NS + half * 128)) * DF + h * DHH + d];
    #pragma unroll 4
    for (int i = 0; i < 128; ++i)
        acc += a_s[half * 128 + i] * vp[(size_t)i * DF];
    __shared__ float red[256];
    red[t] = acc;
    __syncthreads();
    if (t < 128) ctx[(size_t)b * DF + h * DHH + t] = red[t] + red[t + 128];
}

// ---------------- classifier: build combined bf16 [NN, 2*DF] (swizzled) -----
__global__ __launch_bounds__(256) void combined_kernel(
    const float* __restrict__ feats, const float* __restrict__ imp,
    const float* __restrict__ abuf, __hip_bfloat16* __restrict__ comb)
{
    int n = blockIdx.x;
    int t = threadIdx.x;
    int b = n >> 8;
    float im = imp[n];
    const int sw = (n & 7) << 3;
    #pragma unroll
    for (int rep = 0; rep < 4; ++rep) {
        int f = t + rep * 256;
        float v = (f < DF) ? feats[(size_t)n * DF + f] * im
                           : abuf[(size_t)b * DF + (f - DF)];
        comb[(size_t)n * (2 * DF) + (f ^ sw)] = __float2bfloat16(v);
    }
}

// sum 4 split-K partials + bias + relu, then x Wn2
// 4 threads per node (tq = t&3, 32 kk each) -> 64 blocks, shfl-reduced.
__global__ __launch_bounds__(256) void cls2_kernel(
    const float* __restrict__ hidden4, const float* __restrict__ bn1,
    const float* __restrict__ Wn2, const float* __restrict__ bn2,
    float* __restrict__ out)
{
    __shared__ float w2[256];
    __shared__ float b1s[128];
    int t = threadIdx.x;
    w2[t] = Wn2[t];
    if (t < 128) b1s[t] = bn1[t];
    __syncthreads();
    int n = blockIdx.x * 64 + (t >> 2);
    int tq = t & 3;
    const float* hp = &hidden4[(size_t)n * 128];
    const size_t ps = (size_t)NN * 128;
    float p0 = 0.f, p1 = 0.f;
    int k0 = tq * 32;
    #pragma unroll 4
    for (int kk = k0; kk < k0 + 32; ++kk) {
        float hv = hp[kk] + hp[ps + kk] + hp[2 * ps + kk] + hp[3 * ps + kk] + b1s[kk];
        hv = fmaxf(hv, 0.f);
        p0 += hv * w2[kk * 2 + 0];
        p1 += hv * w2[kk * 2 + 1];
    }
    p0 += __shfl_xor(p0, 1); p0 += __shfl_xor(p0, 2);
    p1 += __shfl_xor(p1, 1); p1 += __shfl_xor(p1, 2);
    if (tq == 0) {
        out[n * 2 + 0] = p0 + bn2[0];
        out[n * 2 + 1] = p1 + bn2[1];
    }
}

extern "C" void kernel_launch(void* const* d_in, const int* in_sizes, int n_in,
                              void* d_out, int out_size, void* d_ws, size_t ws_size,
                              hipStream_t stream) {
    const float* feat = (const float*)d_in[0];
    const float* hyp  = (const float*)d_in[1];
    const int*   esrc = (const int*)d_in[2];
    const int*   edst = (const int*)d_in[3];
    const float* W1   = (const float*)d_in[4];
    const float* al1  = (const float*)d_in[5];
    const float* ar1  = (const float*)d_in[6];
    const float* b1   = (const float*)d_in[7];
    const float* W2   = (const float*)d_in[8];
    const float* al2  = (const float*)d_in[9];
    const float* ar2  = (const float*)d_in[10];
    const float* b2   = (const float*)d_in[11];
    const float* Wq = (const float*)d_in[12]; const float* bq = (const float*)d_in[13];
    const float* Wk = (const float*)d_in[14]; const float* bk = (const float*)d_in[15];
    const float* Wv = (const float*)d_in[16]; const float* bv = (const float*)d_in[17];
    const float* Wo = (const float*)d_in[18]; const float* bo = (const float*)d_in[19];
    const float* Wn1 = (const float*)d_in[20]; const float* bn1 = (const float*)d_in[21];
    const float* Wn2 = (const float*)d_in[22]; const float* bn2 = (const float*)d_in[23];

    char* ws = (char*)d_ws;
    size_t off = 0;
    auto alloc = [&](size_t bytes) -> void* {
        void* p = ws + off;
        off += (bytes + 255) & ~(size_t)255;
        return p;
    };
    unsigned char* Z = (unsigned char*)alloc((size_t)NREL * NN * DF);     // fp8
    float* el     = (float*)alloc((size_t)NREL * NN * NHD * 4);
    float* er     = (float*)alloc((size_t)NREL * NN * NHD * 4);
    int* rowptr   = (int*)alloc((size_t)NREL * (NN + 1) * 4);
    int* rowptr2  = (int*)alloc((size_t)(NN + 1) * 4);
    int* woff     = (int*)alloc((size_t)NREL * NN * 4);
    int* srcCSR   = (int*)alloc((size_t)NREL * NE * 4);
    int* eidCSR   = (int*)alloc((size_t)NREL * NE * 4);
    int* cnt      = (int*)alloc((size_t)NREL * NN * 4);
    int* croff    = (int*)alloc((size_t)NREL * NN * 4);
    int* srcPk    = (int*)alloc((size_t)NREL * NE * 4);
    float* alphaPk= (float*)alloc((size_t)NREL * NE * NHD * 4);
    float* bsum1  = (float*)alloc((size_t)DF * 4);
    float* bsum2  = (float*)alloc((size_t)DF * 4);
    float* bkv    = (float*)alloc((size_t)2 * DF * 4);
    float* h1     = (float*)alloc((size_t)NN * DF * 4);
    float* feats  = (float*)alloc((size_t)NN * DF * 4);
    float* imp    = (float*)alloc((size_t)NN * 4);
    float* kvbuf  = (float*)alloc((size_t)2 * NN * DF * 4);
    float* qbuf   = (float*)alloc((size_t)NB * DF * 4);
    float* ctxb   = (float*)alloc((size_t)NB * DF * 4);
    float* abuf   = (float*)alloc((size_t)NB * DF * 4);
    float* scoresb= (float*)alloc((size_t)NB * NHD * NS * 4);
    float* hidden4= (float*)alloc((size_t)4 * NN * 128 * 4);
    __hip_bfloat16* featbf  = (__hip_bfloat16*)alloc((size_t)NN * DF * 2);
    __hip_bfloat16* h1bf    = (__hip_bfloat16*)alloc((size_t)NN * DF * 2);
    __hip_bfloat16* featsbf = (__hip_bfloat16*)alloc((size_t)NN * DF * 2);
    __hip_bfloat16* combbf  = (__hip_bfloat16*)alloc((size_t)NN * 2 * DF * 2);
    __hip_bfloat16* Wt1 = (__hip_bfloat16*)alloc((size_t)NREL * DF * DF * 2);
    __hip_bfloat16* Wt2 = (__hip_bfloat16*)alloc((size_t)NREL * DF * DF * 2);
    __hip_bfloat16* WtKV = (__hip_bfloat16*)alloc((size_t)2 * DF * DF * 2);
    __hip_bfloat16* Wn1t = (__hip_bfloat16*)alloc((size_t)(2 * DF) * 128 * 2);
    if (off > ws_size) return;

    float* logits = (float*)d_out;
    float* attn   = (float*)d_out + (size_t)NN * 2;
    float* kbuf = kvbuf;
    float* vbuf = kvbuf + (size_t)NN * DF;

    // ---- prep: zero cnt/imp, cast+swizzle feat, bias sums, bkv concat ----
    prep_kernel<<<1026 + NREL * NN / 256, 256, 0, stream>>>(
        feat, (unsigned short*)featbf, b1, b2, bk, bv, bsum1, bsum2, bkv, cnt, imp);

    // ---- CSR build (shared by both layers) ----
    count_kernel<<<NREL * NE / 256, 256, 0, stream>>>(edst, cnt);
    scan_kernel<<<NREL + 1, 1024, 0, stream>>>(cnt, rowptr, woff, rowptr2, croff);
    fill_kernel<<<NREL * NE / 256, 256, 0, stream>>>(edst, esrc, woff, srcCSR, eidCSR);

    // ---- weight transposes (bf16, K-chunk swizzled); W1+W2+Wk+Wv merged ----
    transw2_kernel<<<dim3(DF / 32, DF / 32, 2 * NREL + 2), 256, 0, stream>>>(
        W1, W2, Wk, Wv, Wt1, Wt2, WtKV);
    transw_kernel<<<dim3(2 * DF / 32, 128 / 32, 1), 256, 0, stream>>>(Wn1, Wn1t, 2 * DF, 128);

    // ---- layer 1: 256x128 triple-buffered Z-GEMM (grid = 5 x 256 exactly) --
    zgemm3<<<dim3(DF / 128, NN / 256, NREL), 1024, 0, stream>>>(
        featbf, Wt1, Z, al1, ar1, el, er);
    alpha_kernel<<<NREL * NN / 256, 256, 0, stream>>>(
        el, er, rowptr, rowptr2, croff, srcCSR, eidCSR, alphaPk, srcPk, attn, imp);
    aggc_kernel<<<NN, 256, 0, stream>>>(Z, rowptr2, srcPk, alphaPk, bsum1,
                                        feat, h1, h1bf, 1);

    // ---- layer 2 ----
    zgemm3<<<dim3(DF / 128, NN / 256, NREL), 1024, 0, stream>>>(
        h1bf, Wt2, Z, al2, ar2, el, er);
    alpha_kernel<<<NREL * NN / 256, 256, 0, stream>>>(
        el, er, rowptr, rowptr2, croff, srcCSR, eidCSR, alphaPk, srcPk, nullptr, nullptr);
    aggc_kernel<<<NN, 256, 0, stream>>>(Z, rowptr2, srcPk, alphaPk, bsum2,
                                        h1, feats, featsbf, 0);

    // ---- MHA (KV MFMA + 4 small kernels) ----
    mfma_gemm<float, false, false><<<dim3(DF / 128, NN / 128, 2), 256, 0, stream>>>(
        featsbf, WtKV, bkv, DF, kvbuf, NN, DF, DF, DF, nullptr, nullptr, nullptr, nullptr);
    gemm_kernel<float><<<dim3(DF / 64, 1, 1), 256, 0, stream>>>(
        hyp, Wq, bq, qbuf, NB, DF, DF);
    mha_scores<<<dim3(NB, NS / 4), 256, 0, stream>>>(qbuf, kbuf, scoresb);
    mha_ctx<<<dim3(NB, NHD), 256, 0, stream>>>(scoresb, vbuf, ctxb);
    gemm_kernel<float><<<dim3(DF / 64, 1, 1), 256, 0, stream>>>(
        ctxb, Wo, bo, abuf, NB, DF, DF);

    // ---- classifier (split-K=4, partials summed in cls2) ----
    combined_kernel<<<NN, 256, 0, stream>>>(feats, imp, abuf, combbf);
    mfma_gemm<float, false, false, true><<<dim3(1, NN / 128, 4), 256, 0, stream>>>(
        combbf, Wn1t, nullptr, 0, hidden4, NN, 128, 256, 2 * DF,
        nullptr, nullptr, nullptr, nullptr);
    cls2_kernel<<<NN / 64, 256, 0, stream>>>(hidden4, bn1, Wn2, bn2, logits);
}

// Round 9
// 579.924 us; speedup vs baseline: 1.0181x; 1.0181x over previous
//
#include <hip/hip_runtime.h>
#include <hip/hip_bf16.h>
#include <math.h>

#define NREL 20
#define NN   4096
#define NE   16384
#define DF   512      // flattened feature width (H*HID)
#define NHD  4        // GAT heads
#define DHH  128      // per-head dim
#define NB   16       // graphs
#define NS   256      // nodes per graph

typedef __attribute__((ext_vector_type(8))) __bf16 bf16x8;
typedef __attribute__((ext_vector_type(4))) float f32x4;
typedef __attribute__((ext_vector_type(2))) float f32x2;

struct f8 { unsigned char b; };                         // fp8 e4m3 (OCP) storage

__device__ inline float bf2f(unsigned short u) {
    union { float f; unsigned int i; } c; c.i = ((unsigned int)u) << 16; return c.f;
}
__device__ inline unsigned short f2bu(float f) {
    union { __hip_bfloat16 b; unsigned short u; } c; c.b = __float2bfloat16(f); return c.u;
}
__device__ inline void storeOut(float* p, float v) { *p = v; }
__device__ inline void storeOut(__hip_bfloat16* p, float v) { *p = __float2bfloat16(v); }

__device__ inline void load_lds16(const __hip_bfloat16* g, __hip_bfloat16* l) {
    __builtin_amdgcn_global_load_lds(
        (const __attribute__((address_space(1))) unsigned int*)(const void*)g,
        (__attribute__((address_space(3))) unsigned int*)(void*)l, 16, 0, 0);
}

// K-chunk swizzle, 2-bit (row bits [2:1]): XOR the 8-elem chunk id bits [1:0]
// (k bits [4:3]) with (row>>1)&3. Applied ONCE, at the producer. Consumers
// stage LINEAR slabs (the swizzled layout lands in LDS as-is) and un-swizzle
// on the fragment read with swr=(m15>>1)&3. Rule #21: swizzle is
// producer+read-side only — round 8's consumer-side source pre-swizzle
// CANCELLED the producer swizzle and broke A/B K-chunk pairing.
__device__ inline int kswz(int f, int row) { return f ^ ((((row) >> 1) & 3) << 3); }

// ---------------- prep: zero cnt/imp, cast+swizzle feat, bias sums ----------
__global__ __launch_bounds__(256) void prep_kernel(
    const float* __restrict__ feat, unsigned short* __restrict__ featbf,
    const float* __restrict__ b1, const float* __restrict__ b2,
    const float* __restrict__ bk, const float* __restrict__ bv,
    float* __restrict__ bsum1, float* __restrict__ bsum2,
    float* __restrict__ bkv, int* __restrict__ cnt, float* __restrict__ imp)
{
    int blk = blockIdx.x, t = threadIdx.x;
    if (blk < 1024) {
        int idx = blk * 256 + t;                        // chunk id < NN*DF/8
        int row = idx >> 6;                             // 64 chunks per row
        int f = (idx & 63) * 8;
        int fs = kswz(f, row);
        const float4* ip = (const float4*)&feat[(size_t)row * DF + f];
        float4 v0 = ip[0], v1 = ip[1];
        union { unsigned short u[8]; uint4 q; } o;
        o.u[0] = f2bu(v0.x); o.u[1] = f2bu(v0.y); o.u[2] = f2bu(v0.z); o.u[3] = f2bu(v0.w);
        o.u[4] = f2bu(v1.x); o.u[5] = f2bu(v1.y); o.u[6] = f2bu(v1.z); o.u[7] = f2bu(v1.w);
        *(uint4*)(featbf + (size_t)row * DF + fs) = o.q;
    } else if (blk == 1024) {
        #pragma unroll
        for (int rep = 0; rep < 2; ++rep) {
            int f = t + rep * 256;
            float s1 = 0.f, s2 = 0.f;
            #pragma unroll
            for (int r = 0; r < NREL; ++r) { s1 += b1[r * DF + f]; s2 += b2[r * DF + f]; }
            bsum1[f] = s1; bsum2[f] = s2;
        }
        for (int i = t; i < NN; i += 256) imp[i] = 0.f;
    } else if (blk == 1025) {
        #pragma unroll
        for (int j = 0; j < 4; ++j) {
            int f = t + j * 256;
            bkv[f] = (f < DF) ? bk[f] : bv[f - DF];
        }
    } else {
        int idx = (blk - 1026) * 256 + t;               // < NREL*NN
        cnt[idx] = 0;
    }
}

// ---------------- CSR build ----------------
__global__ void count_kernel(const int* __restrict__ dst, int* __restrict__ cnt) {
    int idx = blockIdx.x * 256 + threadIdx.x;          // < NREL*NE
    int r = idx / NE;
    atomicAdd(&cnt[r * NN + dst[idx]], 1);
}

__global__ void scan_kernel(const int* __restrict__ cnt, int* __restrict__ rowptr,
                            int* __restrict__ woff, int* __restrict__ rowptr2,
                            int* __restrict__ croff) {
    int r = blockIdx.x;
    int t = threadIdx.x;                                // 1024 threads
    __shared__ int sums[1024];
    int v[4]; int local = 0;
    if (r < NREL) {
        #pragma unroll
        for (int j = 0; j < 4; ++j) { v[j] = cnt[r * NN + t * 4 + j]; local += v[j]; }
    } else {
        #pragma unroll
        for (int j = 0; j < 4; ++j) {
            int s = 0;
            for (int rel = 0; rel < NREL; ++rel) {
                croff[rel * NN + t * 4 + j] = s;
                s += cnt[rel * NN + t * 4 + j];
            }
            v[j] = s; local += s;
        }
    }
    sums[t] = local;
    __syncthreads();
    for (int off = 1; off < 1024; off <<= 1) {
        int x = (t >= off) ? sums[t - off] : 0;
        __syncthreads();
        sums[t] += x;
        __syncthreads();
    }
    int run = (t == 0) ? 0 : sums[t - 1];               // exclusive prefix
    if (r < NREL) {
        #pragma unroll
        for (int j = 0; j < 4; ++j) {
            rowptr[r * (NN + 1) + t * 4 + j] = run;
            woff[r * NN + t * 4 + j] = run;
            run += v[j];
        }
        if (t == 1023) rowptr[r * (NN + 1) + NN] = run;
    } else {
        #pragma unroll
        for (int j = 0; j < 4; ++j) { rowptr2[t * 4 + j] = run; run += v[j]; }
        if (t == 1023) rowptr2[NN] = run;
    }
}

__global__ void fill_kernel(const int* __restrict__ dst, const int* __restrict__ src,
                            int* __restrict__ woff, int* __restrict__ srcCSR,
                            int* __restrict__ eidCSR) {
    int idx = blockIdx.x * 256 + threadIdx.x;
    int r = idx / NE; int e = idx % NE;
    int pos = atomicAdd(&woff[r * NN + dst[idx]], 1);
    srcCSR[r * NE + pos] = src[idx];
    eidCSR[r * NE + pos] = e;
}

// ---------------- W[r][K][N] fp32 -> Wt[r][N][K] bf16 (transpose+cast+swz) --
__global__ __launch_bounds__(256) void transw_kernel(
    const float* __restrict__ W, __hip_bfloat16* __restrict__ Wt, int K, int N)
{
    int r = blockIdx.z;
    __shared__ float t[32][33];
    int k0 = blockIdx.x * 32, n0 = blockIdx.y * 32;
    int tx = threadIdx.x % 32, ty = threadIdx.x / 32;   // 8 rows
    #pragma unroll
    for (int kk = ty; kk < 32; kk += 8)
        t[kk][tx] = W[((size_t)r * K + k0 + kk) * N + n0 + tx];
    __syncthreads();
    #pragma unroll
    for (int nn = ty; nn < 32; nn += 8) {
        int row = n0 + nn;
        Wt[((size_t)r * N + row) * K + kswz(k0 + tx, row)] = __float2bfloat16(t[tx][nn]);
    }
}

// merged W1+W2+Wk+Wv transpose: z in [0, 2*NREL+2)
__global__ __launch_bounds__(256) void transw2_kernel(
    const float* __restrict__ W1, const float* __restrict__ W2,
    const float* __restrict__ Wk, const float* __restrict__ Wv,
    __hip_bfloat16* __restrict__ Wt1, __hip_bfloat16* __restrict__ Wt2,
    __hip_bfloat16* __restrict__ WtKV)
{
    int z = blockIdx.z;
    const float* Wsrc; __hip_bfloat16* Wdst;
    if (z < NREL)           { Wsrc = W1 + (size_t)z * DF * DF;          Wdst = Wt1 + (size_t)z * DF * DF; }
    else if (z < 2 * NREL)  { Wsrc = W2 + (size_t)(z - NREL) * DF * DF; Wdst = Wt2 + (size_t)(z - NREL) * DF * DF; }
    else if (z == 2 * NREL) { Wsrc = Wk;                                Wdst = WtKV; }
    else                    { Wsrc = Wv;                                Wdst = WtKV + (size_t)DF * DF; }
    __shared__ float t[32][33];
    int k0 = blockIdx.x * 32, n0 = blockIdx.y * 32;
    int tx = threadIdx.x % 32, ty = threadIdx.x / 32;
    #pragma unroll
    for (int kk = ty; kk < 32; kk += 8)
        t[kk][tx] = Wsrc[(size_t)(k0 + kk) * DF + n0 + tx];
    __syncthreads();
    #pragma unroll
    for (int nn = ty; nn < 32; nn += 8) {
        int row = n0 + nn;
        Wdst[(size_t)row * DF + kswz(k0 + tx, row)] = __float2bfloat16(t[tx][nn]);
    }
}

// ---------------- 256x256 Z-GEMM, BK=32, 64 KB LDS -> 2 blocks/CU -----------
// Round-6 compute shape kept exactly (16 waves 4x4, 64x64/wave, acc[4][4]);
// BK 64->32 halves LDS to 64 KB so TWO blocks co-reside per CU (8 waves/SIMD)
// — an independent block fills every barrier stall (m114 co-scheduling).
// Staging is LINEAR (producer data already swizzled; read-side q^swr
// un-swizzles — round-8 bug was an extra source-side swizzle that cancelled).
// Per K-tile (16 tiles of K=32):
//   read a[4],b[4] (8 ds_read) ; lgkm0 ; barrier (buf drained by all waves)
//   stage kt+2 -> buf (2 global_load_lds) ; 16 MFMA
//   vmcnt(2) counted (kt+1 arrival only; kt+2 stays in flight) ; barrier
// Accumulation: kt ascending = same global K order as rounds 0-7 ->
// bitwise-identical accumulators, absmax must not move.
__global__ __launch_bounds__(1024) void zgemmd(
    const __hip_bfloat16* __restrict__ A,
    const __hip_bfloat16* __restrict__ BtAll,
    unsigned char* __restrict__ Zall,
    const float* __restrict__ al, const float* __restrict__ ar,
    float* __restrict__ el, float* __restrict__ er)
{
    const int r = blockIdx.z;
    const __hip_bfloat16* Bt = BtAll + (size_t)r * DF * DF;
    unsigned char* Z = Zall + (size_t)r * NN * DF;
    const int rowBase = blockIdx.y * 256;
    const int colBase = blockIdx.x * 256;
    __shared__ __hip_bfloat16 lds[32768];               // 64 KB total
    // A buf b: lds + b*8192 ([256][32]); B buf b: lds + 16384 + b*8192
    const int tid = threadIdx.x;
    const int w = tid >> 6, l = tid & 63;
    const int wr = w >> 2, wc = w & 3;                  // 4 x 4 wave grid
    const int m15 = l & 15, q = l >> 4;
    const int swr = (m15 >> 1) & 3;

    // staging: thread covers (row = tid>>2, chunk = tid&3); LINEAR source
    // (data pre-swizzled by the producer), LDS dest linear (tid*8 elems).
    const int sRow = tid >> 2;
    const __hip_bfloat16* Ag = A + (size_t)(rowBase + sRow) * DF + (tid & 3) * 8;
    const __hip_bfloat16* Bg = Bt + (size_t)(colBase + sRow) * DF + (tid & 3) * 8;
    __hip_bfloat16* AsT = lds + tid * 8;
    __hip_bfloat16* BsT = lds + 16384 + tid * 8;

#define STAGE(buf, kt) do { \
        load_lds16(Ag + (kt) * 32, AsT + (buf) * 8192); \
        load_lds16(Bg + (kt) * 32, BsT + (buf) * 8192); } while (0)

    f32x4 acc[4][4];
    #pragma unroll
    for (int i = 0; i < 4; ++i)
        #pragma unroll
        for (int j = 0; j < 4; ++j) acc[i][j] = (f32x4){0.f, 0.f, 0.f, 0.f};

    const int NT = DF / 32;                             // 16 K-tiles
    STAGE(0, 0); STAGE(1, 1);
    asm volatile("s_waitcnt vmcnt(2)" ::: "memory");
    __builtin_amdgcn_s_barrier();
    __builtin_amdgcn_sched_barrier(0);

    bf16x8 a[4], b[4];
    for (int kt = 0; kt < NT; ++kt) {
        const int buf = kt & 1;
        const int aOff = buf * 8192;
        const int bOff = 16384 + buf * 8192;
        #pragma unroll
        for (int i = 0; i < 4; ++i)
            a[i] = *(const bf16x8*)&lds[aOff + (wr * 64 + i * 16 + m15) * 32 + (q ^ swr) * 8];
        #pragma unroll
        for (int j = 0; j < 4; ++j)
            b[j] = *(const bf16x8*)&lds[bOff + (wc * 64 + j * 16 + m15) * 32 + (q ^ swr) * 8];
        asm volatile("s_waitcnt lgkmcnt(0)" ::: "memory");
        __builtin_amdgcn_sched_barrier(0);
        __builtin_amdgcn_s_barrier();                   // buf drained by all waves
        __builtin_amdgcn_sched_barrier(0);
        if (kt + 2 < NT) STAGE(buf, kt + 2);            // overwrite drained buf
        __builtin_amdgcn_sched_barrier(0);
        __builtin_amdgcn_s_setprio(1);
        #pragma unroll
        for (int i = 0; i < 4; ++i)
            #pragma unroll
            for (int j = 0; j < 4; ++j)
                acc[i][j] = __builtin_amdgcn_mfma_f32_16x16x32_bf16(a[i], b[j], acc[i][j], 0, 0, 0);
        __builtin_amdgcn_s_setprio(0);
        if (kt + 2 < NT)      { asm volatile("s_waitcnt vmcnt(2)" ::: "memory"); }
        else if (kt + 1 < NT) { asm volatile("s_waitcnt vmcnt(0)" ::: "memory"); }
        __builtin_amdgcn_s_barrier();
        __builtin_amdgcn_sched_barrier(0);
    }
#undef STAGE

    // ---- epilogue: fp8 pack through LDS (full 64 KB), coalesced store ----
    unsigned char* cbuf = (unsigned char*)lds;
    #pragma unroll
    for (int i = 0; i < 4; ++i)
        #pragma unroll
        for (int j = 0; j < 4; ++j) {
            int colL = wc * 64 + j * 16 + m15;
            #pragma unroll
            for (int reg = 0; reg < 4; ++reg) {
                int rowL = wr * 64 + i * 16 + q * 4 + reg;
                unsigned int pk = __builtin_amdgcn_cvt_pk_fp8_f32(
                    acc[i][j][reg], acc[i][j][reg], 0, false);
                cbuf[rowL * 256 + colL] = (unsigned char)(pk & 0xFF);
            }
        }
    __syncthreads();
    {
        int rowL = tid >> 2, colL = (tid & 3) * 64;
        const uint4* src = (const uint4*)&cbuf[rowL * 256 + colL];
        uint4* dst = (uint4*)(Z + (size_t)(rowBase + rowL) * DF + colBase + colL);
        #pragma unroll
        for (int x = 0; x < 4; ++x) dst[x] = src[x];
    }
    __syncthreads();                                    // cbuf reads done before eP reuse

    // ---- el/er fuse: per-row dot with al/ar, reduce over 16 col-lanes ----
    float alv[4], arv[4];
    #pragma unroll
    for (int j = 0; j < 4; ++j) {
        int col = colBase + wc * 64 + j * 16 + m15;
        alv[j] = al[r * DF + col];
        arv[j] = ar[r * DF + col];
    }
    float pe[4][4], pr[4][4];
    #pragma unroll
    for (int i = 0; i < 4; ++i)
        #pragma unroll
        for (int reg = 0; reg < 4; ++reg) {
            float se = 0.f, sr = 0.f;
            #pragma unroll
            for (int j = 0; j < 4; ++j) {
                se += acc[i][j][reg] * alv[j];
                sr += acc[i][j][reg] * arv[j];
            }
            pe[i][reg] = se; pr[i][reg] = sr;
        }
    #pragma unroll
    for (int off = 1; off < 16; off <<= 1)
        #pragma unroll
        for (int i = 0; i < 4; ++i)
            #pragma unroll
            for (int reg = 0; reg < 4; ++reg) {
                pe[i][reg] += __shfl_xor(pe[i][reg], off);
                pr[i][reg] += __shfl_xor(pr[i][reg], off);
            }
    float* eP = (float*)lds;                            // [2 heads][256 rows][2 strips]
    float* rP = eP + 1024;
    if (m15 == 0) {
        int hh = wc >> 1, strip = wc & 1;
        #pragma unroll
        for (int i = 0; i < 4; ++i)
            #pragma unroll
            for (int reg = 0; reg < 4; ++reg) {
                int rowL = wr * 64 + i * 16 + q * 4 + reg;
                eP[(hh * 256 + rowL) * 2 + strip] = pe[i][reg];
                rP[(hh * 256 + rowL) * 2 + strip] = pr[i][reg];
            }
    }
    __syncthreads();
    if (tid < 512) {
        int rowL = tid & 255, hh = tid >> 8;
        int head = (colBase >> 7) + hh;
        size_t idx = ((size_t)r * NN + rowBase + rowL) * NHD + head;
        el[idx] = eP[(hh * 256 + rowL) * 2] + eP[(hh * 256 + rowL) * 2 + 1];
        er[idx] = rP[(hh * 256 + rowL) * 2] + rP[(hh * 256 + rowL) * 2 + 1];
    }
}

// ---------------- bf16 MFMA GEMM: C[r] = A @ Bt[r]^T (+bias, opt relu) ------
// 128^2 tile, kept for KV projection and the split-K classifier GEMM.
template <typename OutT, bool RELU, bool FUSE, bool SPLITK = false>
__global__ __launch_bounds__(256) void mfma_gemm(
    const __hip_bfloat16* __restrict__ A,
    const __hip_bfloat16* __restrict__ BtAll,
    const float* __restrict__ bias, int biasStride,
    OutT* __restrict__ Call, int M, int N, int K, int lda,
    const float* __restrict__ al, const float* __restrict__ ar,
    float* __restrict__ el, float* __restrict__ er)
{
    int r = blockIdx.z;
    const __hip_bfloat16* Bt;
    int koff;
    if (SPLITK) { Bt = BtAll;                         koff = r * K; }
    else        { Bt = BtAll + (size_t)r * N * lda;   koff = 0; }
    OutT* C = Call + (size_t)r * M * N;
    const int rowBase = blockIdx.y * 128;
    const int colBase = blockIdx.x * 128;
    __shared__ __hip_bfloat16 As[128 * 64];
    __shared__ __hip_bfloat16 Bs[128 * 64];
    const int tid = threadIdx.x;
    const int w = tid >> 6, l = tid & 63;
    const int wr = w >> 1, wc = w & 1;
    const int m15 = l & 15, q = l >> 4;
    const int sRow = tid >> 3;                          // 0..31 (call adds 32*c)
    const int sChk = tid & 7;
    const __hip_bfloat16* Ag = A + (size_t)(rowBase + sRow) * lda + koff + sChk * 8;
    const __hip_bfloat16* Bg = Bt + (size_t)(colBase + sRow) * lda + koff + sChk * 8;
    __hip_bfloat16* Asl = As + tid * 8;
    __hip_bfloat16* Bsl = Bs + tid * 8;
    const int swr = (m15 >> 1) & 3;                     // read-side 2-bit swizzle

    f32x4 acc[4][4];
    #pragma unroll
    for (int i = 0; i < 4; ++i)
        #pragma unroll
        for (int j = 0; j < 4; ++j) acc[i][j] = (f32x4){0.f, 0.f, 0.f, 0.f};

    for (int k0 = 0; k0 < K; k0 += 64) {
        #pragma unroll
        for (int c = 0; c < 4; ++c) {
            load_lds16(Ag + (size_t)c * 32 * lda + k0, Asl + c * 2048);
            load_lds16(Bg + (size_t)c * 32 * lda + k0, Bsl + c * 2048);
        }
        __syncthreads();
        #pragma unroll
        for (int g = 0; g < 2; ++g) {
            bf16x8 a[4], b[4];
            #pragma unroll
            for (int i = 0; i < 4; ++i)
                a[i] = *(const bf16x8*)&As[(wr * 64 + i * 16 + m15) * 64 + ((g * 4 + q) ^ swr) * 8];
            #pragma unroll
            for (int j = 0; j < 4; ++j)
                b[j] = *(const bf16x8*)&Bs[(wc * 64 + j * 16 + m15) * 64 + ((g * 4 + q) ^ swr) * 8];
            #pragma unroll
            for (int i = 0; i < 4; ++i)
                #pragma unroll
                for (int j = 0; j < 4; ++j)
                    acc[i][j] = __builtin_amdgcn_mfma_f32_16x16x32_bf16(a[i], b[j], acc[i][j], 0, 0, 0);
        }
        __syncthreads();
    }

    if constexpr (sizeof(OutT) == 1) {
        unsigned char* cbuf = (unsigned char*)As;
        #pragma unroll
        for (int i = 0; i < 4; ++i)
            #pragma unroll
            for (int j = 0; j < 4; ++j) {
                int colL = wc * 64 + j * 16 + m15;
                #pragma unroll
                for (int reg = 0; reg < 4; ++reg) {
                    int rowL = wr * 64 + i * 16 + q * 4 + reg;
                    unsigned int pk = __builtin_amdgcn_cvt_pk_fp8_f32(
                        acc[i][j][reg], acc[i][j][reg], 0, false);
                    cbuf[rowL * 128 + colL] = (unsigned char)(pk & 0xFF);
                }
            }
        __syncthreads();
        int rowL = tid >> 1, colL = (tid & 1) * 64;
        const uint4* src = (const uint4*)&cbuf[rowL * 128 + colL];
        uint4* dst = (uint4*)((unsigned char*)C + (size_t)(rowBase + rowL) * N
                              + colBase + colL);
        #pragma unroll
        for (int x = 0; x < 4; ++x) dst[x] = src[x];
    } else {
        #pragma unroll
        for (int i = 0; i < 4; ++i) {
            #pragma unroll
            for (int j = 0; j < 4; ++j) {
                int col = colBase + wc * 64 + j * 16 + m15;
                float bv = bias ? bias[r * biasStride + col] : 0.f;
                #pragma unroll
                for (int reg = 0; reg < 4; ++reg) {
                    int row = rowBase + wr * 64 + i * 16 + q * 4 + reg;
                    float v = acc[i][j][reg] + bv;
                    if (RELU) v = fmaxf(v, 0.f);
                    storeOut(&C[(size_t)row * N + col], v);
                }
            }
        }
    }

    if (FUSE) {
        float alv[4], arv[4];
        #pragma unroll
        for (int j = 0; j < 4; ++j) {
            int col = colBase + wc * 64 + j * 16 + m15;
            alv[j] = al[r * DF + col];
            arv[j] = ar[r * DF + col];
        }
        float pe[4][4], pr[4][4];
        #pragma unroll
        for (int i = 0; i < 4; ++i)
            #pragma unroll
            for (int reg = 0; reg < 4; ++reg) {
                float se = 0.f, sr = 0.f;
                #pragma unroll
                for (int j = 0; j < 4; ++j) {
                    se += acc[i][j][reg] * alv[j];
                    sr += acc[i][j][reg] * arv[j];
                }
                pe[i][reg] = se; pr[i][reg] = sr;
            }
        #pragma unroll
        for (int off = 1; off < 16; off <<= 1)
            #pragma unroll
            for (int i = 0; i < 4; ++i)
                #pragma unroll
                for (int reg = 0; reg < 4; ++reg) {
                    pe[i][reg] += __shfl_xor(pe[i][reg], off);
                    pr[i][reg] += __shfl_xor(pr[i][reg], off);
                }
        float* eP = (float*)Bs;
        float* rP = eP + 256;
        if (m15 == 0) {
            #pragma unroll
            for (int i = 0; i < 4; ++i)
                #pragma unroll
                for (int reg = 0; reg < 4; ++reg) {
                    int rowL = wr * 64 + i * 16 + q * 4 + reg;
                    eP[rowL * 2 + wc] = pe[i][reg];
                    rP[rowL * 2 + wc] = pr[i][reg];
                }
        }
        __syncthreads();
        if (tid < 128) {
            int head = colBase >> 7;
            size_t idx = ((size_t)r * NN + rowBase + tid) * NHD + head;
            el[idx] = eP[tid * 2] + eP[tid * 2 + 1];
            er[idx] = rP[tid * 2] + rP[tid * 2 + 1];
        }
    }
}

// ---------------- fp32 VALU GEMM for tiny M (q, ctx projections) ------------
template <typename OutT>
__global__ __launch_bounds__(256) void gemm_kernel(
    const float* __restrict__ A, const float* __restrict__ Bm,
    const float* __restrict__ bias, OutT* __restrict__ C,
    int M, int K, int Nn)
{
    int r = blockIdx.z;
    const float* B = Bm + (size_t)r * K * Nn;
    OutT* Cr = C + (size_t)r * M * Nn;
    int rowBase = blockIdx.y * 64;
    int colBase = blockIdx.x * 64;
    __shared__ float As[64][17];
    __shared__ float Bs[16][64];
    int tid = threadIdx.x;
    int tx = tid % 16, ty = tid / 16;
    float acc[4][4] = {};
    int aRow = tid / 4, aK4 = (tid % 4) * 4;
    int bK = tid / 16, bN4 = (tid % 16) * 4;
    for (int k0 = 0; k0 < K; k0 += 16) {
        int gRow = rowBase + aRow;
        float4 av = make_float4(0.f, 0.f, 0.f, 0.f);
        if (gRow < M) av = *(const float4*)(A + (size_t)gRow * K + k0 + aK4);
        As[aRow][aK4 + 0] = av.x; As[aRow][aK4 + 1] = av.y;
        As[aRow][aK4 + 2] = av.z; As[aRow][aK4 + 3] = av.w;
        float4 bv = *(const float4*)(B + (size_t)(k0 + bK) * Nn + colBase + bN4);
        *(float4*)&Bs[bK][bN4] = bv;
        __syncthreads();
        #pragma unroll
        for (int k = 0; k < 16; ++k) {
            float a[4], b[4];
            #pragma unroll
            for (int i = 0; i < 4; ++i) a[i] = As[ty * 4 + i][k];
            #pragma unroll
            for (int j = 0; j < 4; ++j) b[j] = Bs[k][tx * 4 + j];
            #pragma unroll
            for (int i = 0; i < 4; ++i)
                #pragma unroll
                for (int j = 0; j < 4; ++j) acc[i][j] += a[i] * b[j];
        }
        __syncthreads();
    }
    #pragma unroll
    for (int i = 0; i < 4; ++i) {
        int gRow = rowBase + ty * 4 + i;
        if (gRow >= M) continue;
        #pragma unroll
        for (int j = 0; j < 4; ++j) {
            int gCol = colBase + tx * 4 + j;
            float v = acc[i][j];
            if (bias) v += bias[gCol];
            storeOut(&Cr[(size_t)gRow * Nn + gCol], v);
        }
    }
}

// ---------------- per-(rel,node): den + alpha, pack into combined CSR -------
__global__ __launch_bounds__(256) void alpha_kernel(
    const float* __restrict__ el, const float* __restrict__ er,
    const int* __restrict__ rowptr, const int* __restrict__ rowptr2,
    const int* __restrict__ croff, const int* __restrict__ srcCSR,
    const int* __restrict__ eidCSR,
    float* __restrict__ alphaPk, int* __restrict__ srcPk,
    float* __restrict__ attn, float* __restrict__ imp)
{
    int t = blockIdx.x * 256 + threadIdx.x;             // < NREL*NN
    int r = t / NN, n = t % NN;
    int start = rowptr[r * (NN + 1) + n];
    int d = rowptr[r * (NN + 1) + n + 1] - start;
    if (d == 0) return;
    int pbase = rowptr2[n] + croff[r * NN + n];
    float4 er4 = *(const float4*)&er[((size_t)r * NN + n) * NHD];
    float4 den = make_float4(0.f, 0.f, 0.f, 0.f);
    for (int j = 0; j < d; ++j) {
        int s = srcCSR[r * NE + start + j];
        float4 el4 = *(const float4*)&el[((size_t)r * NN + s) * NHD];
        float v0 = el4.x + er4.x; v0 = v0 > 0.f ? v0 : 0.2f * v0;
        float v1 = el4.y + er4.y; v1 = v1 > 0.f ? v1 : 0.2f * v1;
        float v2 = el4.z + er4.z; v2 = v2 > 0.f ? v2 : 0.2f * v2;
        float v3 = el4.w + er4.w; v3 = v3 > 0.f ? v3 : 0.2f * v3;
        float4 e4 = make_float4(__expf(v0), __expf(v1), __expf(v2), __expf(v3));
        den.x += e4.x; den.y += e4.y; den.z += e4.z; den.w += e4.w;
        *(float4*)&alphaPk[(size_t)(pbase + j) * 4] = e4;
        srcPk[pbase + j] = r * NN + s;                  // direct Z-row index
    }
    float4 inv = make_float4(1.f / den.x, 1.f / den.y, 1.f / den.z, 1.f / den.w);
    float impLoc = 0.f;
    for (int j = 0; j < d; ++j) {
        float4 a4 = *(const float4*)&alphaPk[(size_t)(pbase + j) * 4];
        a4.x *= inv.x; a4.y *= inv.y; a4.z *= inv.z; a4.w *= inv.w;
        *(float4*)&alphaPk[(size_t)(pbase + j) * 4] = a4;
        if (attn) {
            float a = 0.25f * (a4.x + a4.y + a4.z + a4.w);
            attn[r * NE + eidCSR[r * NE + start + j]] = a;
            impLoc += a;
        }
    }
    if (attn) atomicAdd(&imp[n], impLoc);
}

// ---------------- combined aggregation: block per node, 4 waves -------------
__global__ __launch_bounds__(256) void aggc_kernel(
    const unsigned char* __restrict__ Z,
    const int* __restrict__ rowptr2, const int* __restrict__ srcPk,
    const float* __restrict__ alphaPk, const float* __restrict__ bsum,
    const float* __restrict__ hin, float* __restrict__ hout,
    __hip_bfloat16* __restrict__ hout_bf, int applyElu)
{
    int n = blockIdx.x;
    int w = threadIdx.x >> 6, lane = threadIdx.x & 63;
    int h = lane >> 4;
    int base = rowptr2[n];
    int deg = rowptr2[n + 1] - base;
    float acc[8] = {};
    if (deg > 0) {
        int i = w * 4;
        int zz[4]; float aa[4];
        #pragma unroll
        for (int j = 0; j < 4; ++j) {
            int idx = i + j; int cidx = idx < deg ? idx : deg - 1;
            zz[j] = srcPk[base + cidx];
            aa[j] = (idx < deg) ? alphaPk[(size_t)(base + cidx) * 4 + h] : 0.f;
        }
        while (i < deg) {
            int cz[4]; float ca[4];
            #pragma unroll
            for (int j = 0; j < 4; ++j) { cz[j] = zz[j]; ca[j] = aa[j]; }
            int ni = i + 16;
            #pragma unroll
            for (int j = 0; j < 4; ++j) {
                int idx = ni + j; int cidx = idx < deg ? idx : deg - 1;
                zz[j] = srcPk[base + cidx];
                aa[j] = (idx < deg) ? alphaPk[(size_t)(base + cidx) * 4 + h] : 0.f;
            }
            uint2 raw[4];
            #pragma unroll
            for (int j = 0; j < 4; ++j)
                raw[j] = *(const uint2*)&Z[(size_t)cz[j] * DF + lane * 8];
            #pragma unroll
            for (int j = 0; j < 4; ++j) {
                f32x2 f01 = __builtin_amdgcn_cvt_pk_f32_fp8((int)raw[j].x, false);
                f32x2 f23 = __builtin_amdgcn_cvt_pk_f32_fp8((int)raw[j].x, true);
                f32x2 f45 = __builtin_amdgcn_cvt_pk_f32_fp8((int)raw[j].y, false);
                f32x2 f67 = __builtin_amdgcn_cvt_pk_f32_fp8((int)raw[j].y, true);
                acc[0] += ca[j] * f01.x; acc[1] += ca[j] * f01.y;
                acc[2] += ca[j] * f23.x; acc[3] += ca[j] * f23.y;
                acc[4] += ca[j] * f45.x; acc[5] += ca[j] * f45.y;
                acc[6] += ca[j] * f67.x; acc[7] += ca[j] * f67.y;
            }
            i = ni;
        }
    }
    __shared__ float red[4][DF];
    #pragma unroll
    for (int j = 0; j < 8; ++j) red[w][lane * 8 + j] = acc[j];
    __syncthreads();
    const float invR = 1.0f / NREL;
    const int sw = ((n >> 1) & 3) << 3;                 // 2-bit producer swizzle
    int f = threadIdx.x;
    #pragma unroll
    for (int rep = 0; rep < 2; ++rep, f += 256) {
        float v = red[0][f] + red[1][f] + red[2][f] + red[3][f];
        v = (v + bsum[f]) * invR + hin[(size_t)n * DF + f];
        if (applyElu) v = v > 0.f ? v : expm1f(v);
        hout[(size_t)n * DF + f] = v;
        hout_bf[(size_t)n * DF + (f ^ sw)] = __float2bfloat16(v);   // swizzled
    }
}

// ---------------- MHA: scores, then fused softmax+context -------------------
__global__ __launch_bounds__(256) void mha_scores(
    const float* __restrict__ q, const float* __restrict__ k,
    float* __restrict__ scores)
{
    int b = blockIdx.x;
    int w = threadIdx.x >> 6, lane = threadIdx.x & 63;
    int s = blockIdx.y * 4 + w;
    const float4* qp = (const float4*)&q[(size_t)b * DF + lane * 8];
    const float4* kp = (const float4*)&k[((size_t)(b * NS + s)) * DF + lane * 8];
    float4 q0 = qp[0], q1 = qp[1];
    float4 k0 = kp[0], k1 = kp[1];
    float p = q0.x * k0.x + q0.y * k0.y + q0.z * k0.z + q0.w * k0.w
            + q1.x * k1.x + q1.y * k1.y + q1.z * k1.z + q1.w * k1.w;
    #pragma unroll
    for (int off = 1; off < 16; off <<= 1) p += __shfl_xor(p, off);
    if ((lane & 15) == 0) {
        int h = lane >> 4;
        scores[((size_t)(b * NHD + h)) * NS + s] = p * 0.08838834764831845f;
    }
}

// softmax folded in (was a separate mha_soft launch)
__global__ __launch_bounds__(256) void mha_ctx(
    const float* __restrict__ scores, const float* __restrict__ v,
    float* __restrict__ ctx)
{
    int b = blockIdx.x, h = blockIdx.y;
    int t = threadIdx.x;
    int lane = t & 63, w = t >> 6;
    __shared__ float a_s[NS];
    __shared__ float wred[8];
    float sv = scores[((size_t)(b * NHD + h)) * NS + t];
    float mx = sv;
    #pragma unroll
    for (int off = 1; off < 64; off <<= 1) mx = fmaxf(mx, __shfl_xor(mx, off));
    if (lane == 0) wred[w] = mx;
    __syncthreads();
    mx = fmaxf(fmaxf(wred[0], wred[1]), fmaxf(wred[2], wred[3]));
    float e = __expf(sv - mx);
    float sum = e;
    #pragma unroll
    for (int off = 1; off < 64; off <<= 1) sum += __shfl_xor(sum, off);
    if (lane == 0) wred[4 + w] = sum;
    __syncthreads();
    sum = wred[4] + wred[5] + wred[6] + wred[7];
    a_s[t] = e * (1.0f / sum);
    __syncthreads();
    int d = t & 127, half = t >> 7;
    float acc = 0.f;
    const float* vp = &v[((size_t)(b * NS + half * 128)) * DF + h * DHH + d];
    #pragma unroll 4
    for (int i = 0; i < 128; ++i)
        acc += a_s[half * 128 + i] * vp[(size_t)i * DF];
    __shared__ float red[256];
    red[t] = acc;
    __syncthreads();
    if (t < 128) ctx[(size_t)b * DF + h * DHH + t] = red[t] + red[t + 128];
}

// ---------------- classifier: build combined bf16 [NN, 2*DF] (swizzled) -----
__global__ __launch_bounds__(256) void combined_kernel(
    const float* __restrict__ feats, const float* __restrict__ imp,
    const float* __restrict__ abuf, __hip_bfloat16* __restrict__ comb)
{
    int n = blockIdx.x;
    int t = threadIdx.x;
    int b = n >> 8;
    float im = imp[n];
    const int sw = ((n >> 1) & 3) << 3;                 // 2-bit producer swizzle
    #pragma unroll
    for (int rep = 0; rep < 4; ++rep) {
        int f = t + rep * 256;
        float v = (f < DF) ? feats[(size_t)n * DF + f] * im
                           : abuf[(size_t)b * DF + (f - DF)];
        comb[(size_t)n * (2 * DF) + (f ^ sw)] = __float2bfloat16(v);
    }
}

// sum 4 split-K partials + bias + relu, then x Wn2
// 4 threads per node (tq = t&3, 32 kk each) -> 64 blocks, shfl-reduced.
__global__ __launch_bounds__(256) void cls2_kernel(
    const float* __restrict__ hidden4, const float* __restrict__ bn1,
    const float* __restrict__ Wn2, const float* __restrict__ bn2,
    float* __restrict__ out)
{
    __shared__ float w2[256];
    __shared__ float b1s[128];
    int t = threadIdx.x;
    w2[t] = Wn2[t];
    if (t < 128) b1s[t] = bn1[t];
    __syncthreads();
    int n = blockIdx.x * 64 + (t >> 2);
    int tq = t & 3;
    const float* hp = &hidden4[(size_t)n * 128];
    const size_t ps = (size_t)NN * 128;
    float p0 = 0.f, p1 = 0.f;
    int k0 = tq * 32;
    #pragma unroll 4
    for (int kk = k0; kk < k0 + 32; ++kk) {
        float hv = hp[kk] + hp[ps + kk] + hp[2 * ps + kk] + hp[3 * ps + kk] + b1s[kk];
        hv = fmaxf(hv, 0.f);
        p0 += hv * w2[kk * 2 + 0];
        p1 += hv * w2[kk * 2 + 1];
    }
    p0 += __shfl_xor(p0, 1); p0 += __shfl_xor(p0, 2);
    p1 += __shfl_xor(p1, 1); p1 += __shfl_xor(p1, 2);
    if (tq == 0) {
        out[n * 2 + 0] = p0 + bn2[0];
        out[n * 2 + 1] = p1 + bn2[1];
    }
}

extern "C" void kernel_launch(void* const* d_in, const int* in_sizes, int n_in,
                              void* d_out, int out_size, void* d_ws, size_t ws_size,
                              hipStream_t stream) {
    const float* feat = (const float*)d_in[0];
    const float* hyp  = (const float*)d_in[1];
    const int*   esrc = (const int*)d_in[2];
    const int*   edst = (const int*)d_in[3];
    const float* W1   = (const float*)d_in[4];
    const float* al1  = (const float*)d_in[5];
    const float* ar1  = (const float*)d_in[6];
    const float* b1   = (const float*)d_in[7];
    const float* W2   = (const float*)d_in[8];
    const float* al2  = (const float*)d_in[9];
    const float* ar2  = (const float*)d_in[10];
    const float* b2   = (const float*)d_in[11];
    const float* Wq = (const float*)d_in[12]; const float* bq = (const float*)d_in[13];
    const float* Wk = (const float*)d_in[14]; const float* bk = (const float*)d_in[15];
    const float* Wv = (const float*)d_in[16]; const float* bv = (const float*)d_in[17];
    const float* Wo = (const float*)d_in[18]; const float* bo = (const float*)d_in[19];
    const float* Wn1 = (const float*)d_in[20]; const float* bn1 = (const float*)d_in[21];
    const float* Wn2 = (const float*)d_in[22]; const float* bn2 = (const float*)d_in[23];

    char* ws = (char*)d_ws;
    size_t off = 0;
    auto alloc = [&](size_t bytes) -> void* {
        void* p = ws + off;
        off += (bytes + 255) & ~(size_t)255;
        return p;
    };
    unsigned char* Z = (unsigned char*)alloc((size_t)NREL * NN * DF);     // fp8
    float* el     = (float*)alloc((size_t)NREL * NN * NHD * 4);
    float* er     = (float*)alloc((size_t)NREL * NN * NHD * 4);
    int* rowptr   = (int*)alloc((size_t)NREL * (NN + 1) * 4);
    int* rowptr2  = (int*)alloc((size_t)(NN + 1) * 4);
    int* woff     = (int*)alloc((size_t)NREL * NN * 4);
    int* srcCSR   = (int*)alloc((size_t)NREL * NE * 4);
    int* eidCSR   = (int*)alloc((size_t)NREL * NE * 4);
    int* cnt      = (int*)alloc((size_t)NREL * NN * 4);
    int* croff    = (int*)alloc((size_t)NREL * NN * 4);
    int* srcPk    = (int*)alloc((size_t)NREL * NE * 4);
    float* alphaPk= (float*)alloc((size_t)NREL * NE * NHD * 4);
    float* bsum1  = (float*)alloc((size_t)DF * 4);
    float* bsum2  = (float*)alloc((size_t)DF * 4);
    float* bkv    = (float*)alloc((size_t)2 * DF * 4);
    float* h1     = (float*)alloc((size_t)NN * DF * 4);
    float* feats  = (float*)alloc((size_t)NN * DF * 4);
    float* imp    = (float*)alloc((size_t)NN * 4);
    float* kvbuf  = (float*)alloc((size_t)2 * NN * DF * 4);
    float* qbuf   = (float*)alloc((size_t)NB * DF * 4);
    float* ctxb   = (float*)alloc((size_t)NB * DF * 4);
    float* abuf   = (float*)alloc((size_t)NB * DF * 4);
    float* scoresb= (float*)alloc((size_t)NB * NHD * NS * 4);
    float* hidden4= (float*)alloc((size_t)4 * NN * 128 * 4);
    __hip_bfloat16* featbf  = (__hip_bfloat16*)alloc((size_t)NN * DF * 2);
    __hip_bfloat16* h1bf    = (__hip_bfloat16*)alloc((size_t)NN * DF * 2);
    __hip_bfloat16* featsbf = (__hip_bfloat16*)alloc((size_t)NN * DF * 2);
    __hip_bfloat16* combbf  = (__hip_bfloat16*)alloc((size_t)NN * 2 * DF * 2);
    __hip_bfloat16* Wt1 = (__hip_bfloat16*)alloc((size_t)NREL * DF * DF * 2);
    __hip_bfloat16* Wt2 = (__hip_bfloat16*)alloc((size_t)NREL * DF * DF * 2);
    __hip_bfloat16* WtKV = (__hip_bfloat16*)alloc((size_t)2 * DF * DF * 2);
    __hip_bfloat16* Wn1t = (__hip_bfloat16*)alloc((size_t)(2 * DF) * 128 * 2);
    if (off > ws_size) return;

    float* logits = (float*)d_out;
    float* attn   = (float*)d_out + (size_t)NN * 2;
    float* kbuf = kvbuf;
    float* vbuf = kvbuf + (size_t)NN * DF;

    // ---- prep: zero cnt/imp, cast+swizzle feat, bias sums, bkv concat ----
    prep_kernel<<<1026 + NREL * NN / 256, 256, 0, stream>>>(
        feat, (unsigned short*)featbf, b1, b2, bk, bv, bsum1, bsum2, bkv, cnt, imp);

    // ---- CSR build (shared by both layers) ----
    count_kernel<<<NREL * NE / 256, 256, 0, stream>>>(edst, cnt);
    scan_kernel<<<NREL + 1, 1024, 0, stream>>>(cnt, rowptr, woff, rowptr2, croff);
    fill_kernel<<<NREL * NE / 256, 256, 0, stream>>>(edst, esrc, woff, srcCSR, eidCSR);

    // ---- weight transposes (bf16, K-chunk swizzled); W1+W2+Wk+Wv merged ----
    transw2_kernel<<<dim3(DF / 32, DF / 32, 2 * NREL + 2), 256, 0, stream>>>(
        W1, W2, Wk, Wv, Wt1, Wt2, WtKV);
    transw_kernel<<<dim3(2 * DF / 32, 128 / 32, 1), 256, 0, stream>>>(Wn1, Wn1t, 2 * DF, 128);

    // ---- layer 1: 256^2 BK=32 Z-GEMM (64 KB LDS, 2 blocks/CU) ----
    zgemmd<<<dim3(DF / 256, NN / 256, NREL), 1024, 0, stream>>>(
        featbf, Wt1, Z, al1, ar1, el, er);
    alpha_kernel<<<NREL * NN / 256, 256, 0, stream>>>(
        el, er, rowptr, rowptr2, croff, srcCSR, eidCSR, alphaPk, srcPk, attn, imp);
    aggc_kernel<<<NN, 256, 0, stream>>>(Z, rowptr2, srcPk, alphaPk, bsum1,
                                        feat, h1, h1bf, 1);

    // ---- layer 2 ----
    zgemmd<<<dim3(DF / 256, NN / 256, NREL), 1024, 0, stream>>>(
        h1bf, Wt2, Z, al2, ar2, el, er);
    alpha_kernel<<<NREL * NN / 256, 256, 0, stream>>>(
        el, er, rowptr, rowptr2, croff, srcCSR, eidCSR, alphaPk, srcPk, nullptr, nullptr);
    aggc_kernel<<<NN, 256, 0, stream>>>(Z, rowptr2, srcPk, alphaPk, bsum2,
                                        h1, feats, featsbf, 0);

    // ---- MHA (KV MFMA + 4 small kernels) ----
    mfma_gemm<float, false, false><<<dim3(DF / 128, NN / 128, 2), 256, 0, stream>>>(
        featsbf, WtKV, bkv, DF, kvbuf, NN, DF, DF, DF, nullptr, nullptr, nullptr, nullptr);
    gemm_kernel<float><<<dim3(DF / 64, 1, 1), 256, 0, stream>>>(
        hyp, Wq, bq, qbuf, NB, DF, DF);
    mha_scores<<<dim3(NB, NS / 4), 256, 0, stream>>>(qbuf, kbuf, scoresb);
    mha_ctx<<<dim3(NB, NHD), 256, 0, stream>>>(scoresb, vbuf, ctxb);
    gemm_kernel<float><<<dim3(DF / 64, 1, 1), 256, 0, stream>>>(
        ctxb, Wo, bo, abuf, NB, DF, DF);

    // ---- classifier (split-K=4, partials summed in cls2) ----
    combined_kernel<<<NN, 256, 0, stream>>>(feats, imp, abuf, combbf);
    mfma_gemm<float, false, false, true><<<dim3(1, NN / 128, 4), 256, 0, stream>>>(
        combbf, Wn1t, nullptr, 0, hidden4, NN, 128, 256, 2 * DF,
        nullptr, nullptr, nullptr, nullptr);
    cls2_kernel<<<NN / 64, 256, 0, stream>>>(hidden4, bn1, Wn2, bn2, logits);
}

// Round 10
// 553.215 us; speedup vs baseline: 1.0673x; 1.0483x over previous
//
#include <hip/hip_runtime.h>
#include <hip/hip_bf16.h>
#include <math.h>

#define NREL 20
#define NN   4096
#define NE   16384
#define DF   512      // flattened feature width (H*HID)
#define NHD  4        // GAT heads
#define DHH  128      // per-head dim
#define NB   16       // graphs
#define NS   256      // nodes per graph

typedef __attribute__((ext_vector_type(8))) __bf16 bf16x8;
typedef __attribute__((ext_vector_type(4))) float f32x4;
typedef __attribute__((ext_vector_type(2))) float f32x2;

struct f8 { unsigned char b; };                         // fp8 e4m3 (OCP) storage

__device__ inline float bf2f(unsigned short u) {
    union { float f; unsigned int i; } c; c.i = ((unsigned int)u) << 16; return c.f;
}
__device__ inline unsigned short f2bu(float f) {
    union { __hip_bfloat16 b; unsigned short u; } c; c.b = __float2bfloat16(f); return c.u;
}
__device__ inline void storeOut(float* p, float v) { *p = v; }
__device__ inline void storeOut(__hip_bfloat16* p, float v) { *p = __float2bfloat16(v); }

__device__ inline void load_lds16(const __hip_bfloat16* g, __hip_bfloat16* l) {
    __builtin_amdgcn_global_load_lds(
        (const __attribute__((address_space(1))) unsigned int*)(const void*)g,
        (__attribute__((address_space(3))) unsigned int*)(void*)l, 16, 0, 0);
}

// K-chunk swizzle: within each 64-elem K-group, XOR the 8-elem chunk id
// (bits [5:3] of k) with (row&7). Producer-side for all GEMM A/B operands.
// (3-bit variant — matches the round-6 best-measured GEMM configuration.)
__device__ inline int kswz(int f, int row) { return f ^ (((row) & 7) << 3); }

// ---------------- prep: zero cnt/imp, cast+swizzle feat, bias sums ----------
__global__ __launch_bounds__(256) void prep_kernel(
    const float* __restrict__ feat, unsigned short* __restrict__ featbf,
    const float* __restrict__ b1, const float* __restrict__ b2,
    const float* __restrict__ bk, const float* __restrict__ bv,
    float* __restrict__ bsum1, float* __restrict__ bsum2,
    float* __restrict__ bkv, int* __restrict__ cnt, float* __restrict__ imp)
{
    int blk = blockIdx.x, t = threadIdx.x;
    if (blk < 1024) {
        int idx = blk * 256 + t;                        // chunk id < NN*DF/8
        int row = idx >> 6;                             // 64 chunks per row
        int f = (idx & 63) * 8;
        int fs = kswz(f, row);
        const float4* ip = (const float4*)&feat[(size_t)row * DF + f];
        float4 v0 = ip[0], v1 = ip[1];
        union { unsigned short u[8]; uint4 q; } o;
        o.u[0] = f2bu(v0.x); o.u[1] = f2bu(v0.y); o.u[2] = f2bu(v0.z); o.u[3] = f2bu(v0.w);
        o.u[4] = f2bu(v1.x); o.u[5] = f2bu(v1.y); o.u[6] = f2bu(v1.z); o.u[7] = f2bu(v1.w);
        *(uint4*)(featbf + (size_t)row * DF + fs) = o.q;
    } else if (blk == 1024) {
        #pragma unroll
        for (int rep = 0; rep < 2; ++rep) {
            int f = t + rep * 256;
            float s1 = 0.f, s2 = 0.f;
            #pragma unroll
            for (int r = 0; r < NREL; ++r) { s1 += b1[r * DF + f]; s2 += b2[r * DF + f]; }
            bsum1[f] = s1; bsum2[f] = s2;
        }
        for (int i = t; i < NN; i += 256) imp[i] = 0.f;
    } else if (blk == 1025) {
        #pragma unroll
        for (int j = 0; j < 4; ++j) {
            int f = t + j * 256;
            bkv[f] = (f < DF) ? bk[f] : bv[f - DF];
        }
    } else {
        int idx = (blk - 1026) * 256 + t;               // < NREL*NN
        cnt[idx] = 0;
    }
}

// ---------------- CSR build ----------------
__global__ void count_kernel(const int* __restrict__ dst, int* __restrict__ cnt) {
    int idx = blockIdx.x * 256 + threadIdx.x;          // < NREL*NE
    int r = idx / NE;
    atomicAdd(&cnt[r * NN + dst[idx]], 1);
}

__global__ void scan_kernel(const int* __restrict__ cnt, int* __restrict__ rowptr,
                            int* __restrict__ woff, int* __restrict__ rowptr2,
                            int* __restrict__ croff) {
    int r = blockIdx.x;
    int t = threadIdx.x;                                // 1024 threads
    __shared__ int sums[1024];
    int v[4]; int local = 0;
    if (r < NREL) {
        #pragma unroll
        for (int j = 0; j < 4; ++j) { v[j] = cnt[r * NN + t * 4 + j]; local += v[j]; }
    } else {
        #pragma unroll
        for (int j = 0; j < 4; ++j) {
            int s = 0;
            for (int rel = 0; rel < NREL; ++rel) {
                croff[rel * NN + t * 4 + j] = s;
                s += cnt[rel * NN + t * 4 + j];
            }
            v[j] = s; local += s;
        }
    }
    sums[t] = local;
    __syncthreads();
    for (int off = 1; off < 1024; off <<= 1) {
        int x = (t >= off) ? sums[t - off] : 0;
        __syncthreads();
        sums[t] += x;
        __syncthreads();
    }
    int run = (t == 0) ? 0 : sums[t - 1];               // exclusive prefix
    if (r < NREL) {
        #pragma unroll
        for (int j = 0; j < 4; ++j) {
            rowptr[r * (NN + 1) + t * 4 + j] = run;
            woff[r * NN + t * 4 + j] = run;
            run += v[j];
        }
        if (t == 1023) rowptr[r * (NN + 1) + NN] = run;
    } else {
        #pragma unroll
        for (int j = 0; j < 4; ++j) { rowptr2[t * 4 + j] = run; run += v[j]; }
        if (t == 1023) rowptr2[NN] = run;
    }
}

__global__ void fill_kernel(const int* __restrict__ dst, const int* __restrict__ src,
                            int* __restrict__ woff, int* __restrict__ srcCSR,
                            int* __restrict__ eidCSR) {
    int idx = blockIdx.x * 256 + threadIdx.x;
    int r = idx / NE; int e = idx % NE;
    int pos = atomicAdd(&woff[r * NN + dst[idx]], 1);
    srcCSR[r * NE + pos] = src[idx];
    eidCSR[r * NE + pos] = e;
}

// ---------------- W[r][K][N] fp32 -> Wt[r][N][K] bf16 (transpose+cast+swz) --
__global__ __launch_bounds__(256) void transw_kernel(
    const float* __restrict__ W, __hip_bfloat16* __restrict__ Wt, int K, int N)
{
    int r = blockIdx.z;
    __shared__ float t[32][33];
    int k0 = blockIdx.x * 32, n0 = blockIdx.y * 32;
    int tx = threadIdx.x % 32, ty = threadIdx.x / 32;   // 8 rows
    #pragma unroll
    for (int kk = ty; kk < 32; kk += 8)
        t[kk][tx] = W[((size_t)r * K + k0 + kk) * N + n0 + tx];
    __syncthreads();
    #pragma unroll
    for (int nn = ty; nn < 32; nn += 8) {
        int row = n0 + nn;
        Wt[((size_t)r * N + row) * K + kswz(k0 + tx, row)] = __float2bfloat16(t[tx][nn]);
    }
}

// merged W1+W2+Wk+Wv transpose: z in [0, 2*NREL+2)
__global__ __launch_bounds__(256) void transw2_kernel(
    const float* __restrict__ W1, const float* __restrict__ W2,
    const float* __restrict__ Wk, const float* __restrict__ Wv,
    __hip_bfloat16* __restrict__ Wt1, __hip_bfloat16* __restrict__ Wt2,
    __hip_bfloat16* __restrict__ WtKV)
{
    int z = blockIdx.z;
    const float* Wsrc; __hip_bfloat16* Wdst;
    if (z < NREL)           { Wsrc = W1 + (size_t)z * DF * DF;          Wdst = Wt1 + (size_t)z * DF * DF; }
    else if (z < 2 * NREL)  { Wsrc = W2 + (size_t)(z - NREL) * DF * DF; Wdst = Wt2 + (size_t)(z - NREL) * DF * DF; }
    else if (z == 2 * NREL) { Wsrc = Wk;                                Wdst = WtKV; }
    else                    { Wsrc = Wv;                                Wdst = WtKV + (size_t)DF * DF; }
    __shared__ float t[32][33];
    int k0 = blockIdx.x * 32, n0 = blockIdx.y * 32;
    int tx = threadIdx.x % 32, ty = threadIdx.x / 32;
    #pragma unroll
    for (int kk = ty; kk < 32; kk += 8)
        t[kk][tx] = Wsrc[(size_t)(k0 + kk) * DF + n0 + tx];
    __syncthreads();
    #pragma unroll
    for (int nn = ty; nn < 32; nn += 8) {
        int row = n0 + nn;
        Wdst[(size_t)row * DF + kswz(k0 + tx, row)] = __float2bfloat16(t[tx][nn]);
    }
}

// ---------------- 256x256 Z-GEMM, 16 waves / 64x64 per wave (round-6 best) --
// acc[4][4] (64 AGPR) + a[4]+b[4] keeps ~128 regs/wave. BK=64 double-buffered
// 128 KiB LDS. Per K-tile: read ks0 (8 ds_read); lgkm0; 16 MFMA; read ks1;
// lgkm0; barrier; stage kt+2 -> buf (4 loads, under MFMA ks1); 16 MFMA;
// vmcnt(4) counted; barrier. Measured 72.3 us/dispatch — best of 6 schedule
// variants (rounds 2-9); declared structural floor for this session.
__global__ __launch_bounds__(1024) void zgemm16(
    const __hip_bfloat16* __restrict__ A,
    const __hip_bfloat16* __restrict__ BtAll,
    unsigned char* __restrict__ Zall,
    const float* __restrict__ al, const float* __restrict__ ar,
    float* __restrict__ el, float* __restrict__ er)
{
    const int r = blockIdx.z;
    const __hip_bfloat16* Bt = BtAll + (size_t)r * DF * DF;
    unsigned char* Z = Zall + (size_t)r * NN * DF;
    const int rowBase = blockIdx.y * 256;
    const int colBase = blockIdx.x * 256;
    __shared__ __hip_bfloat16 As[2][256][64];           // 64 KB
    __shared__ __hip_bfloat16 Bs[2][256][64];           // 64 KB
    const int tid = threadIdx.x;
    const int w = tid >> 6, l = tid & 63;
    const int wr = w >> 2, wc = w & 3;                  // 4 x 4 wave grid
    const int m15 = l & 15, q = l >> 4;
    const int swr = m15 & 7;

    const __hip_bfloat16* Ag = A + (size_t)(rowBase + (tid >> 3)) * DF + (tid & 7) * 8;
    const __hip_bfloat16* Bg = Bt + (size_t)(colBase + (tid >> 3)) * DF + (tid & 7) * 8;
    __hip_bfloat16* AsT = &As[0][0][0] + tid * 8;
    __hip_bfloat16* BsT = &Bs[0][0][0] + tid * 8;

#define STAGE_A(buf, kt) do { \
        const __hip_bfloat16* s_ = Ag + (kt) * 64; \
        __hip_bfloat16* d_ = AsT + (buf) * 16384; \
        load_lds16(s_, d_); \
        load_lds16(s_ + (size_t)128 * DF, d_ + 8192); } while (0)
#define STAGE_B(buf, kt) do { \
        const __hip_bfloat16* s_ = Bg + (kt) * 64; \
        __hip_bfloat16* d_ = BsT + (buf) * 16384; \
        load_lds16(s_, d_); \
        load_lds16(s_ + (size_t)128 * DF, d_ + 8192); } while (0)

    f32x4 acc[4][4];
    #pragma unroll
    for (int i = 0; i < 4; ++i)
        #pragma unroll
        for (int j = 0; j < 4; ++j) acc[i][j] = (f32x4){0.f, 0.f, 0.f, 0.f};

    const int NT = DF / 64;                             // 8 K-tiles
    STAGE_A(0, 0); STAGE_B(0, 0);
    STAGE_A(1, 1); STAGE_B(1, 1);
    asm volatile("s_waitcnt vmcnt(4)" ::: "memory");
    __builtin_amdgcn_s_barrier();
    __builtin_amdgcn_sched_barrier(0);

    bf16x8 a[4], b[4];
    for (int kt = 0; kt < NT; ++kt) {
        const int buf = kt & 1;
        // ---- ks0 fragment reads ----
        #pragma unroll
        for (int i = 0; i < 4; ++i)
            a[i] = *(const bf16x8*)&As[buf][wr * 64 + i * 16 + m15][(q ^ swr) * 8];
        #pragma unroll
        for (int j = 0; j < 4; ++j)
            b[j] = *(const bf16x8*)&Bs[buf][wc * 64 + j * 16 + m15][(q ^ swr) * 8];
        asm volatile("s_waitcnt lgkmcnt(0)" ::: "memory");
        __builtin_amdgcn_sched_barrier(0);
        __builtin_amdgcn_s_setprio(1);
        #pragma unroll
        for (int i = 0; i < 4; ++i)
            #pragma unroll
            for (int j = 0; j < 4; ++j)
                acc[i][j] = __builtin_amdgcn_mfma_f32_16x16x32_bf16(a[i], b[j], acc[i][j], 0, 0, 0);
        __builtin_amdgcn_s_setprio(0);
        // ---- ks1 fragment reads (frags reused; WAR safe: in-order issue) ----
        #pragma unroll
        for (int i = 0; i < 4; ++i)
            a[i] = *(const bf16x8*)&As[buf][wr * 64 + i * 16 + m15][((4 + q) ^ swr) * 8];
        #pragma unroll
        for (int j = 0; j < 4; ++j)
            b[j] = *(const bf16x8*)&Bs[buf][wc * 64 + j * 16 + m15][((4 + q) ^ swr) * 8];
        asm volatile("s_waitcnt lgkmcnt(0)" ::: "memory");
        __builtin_amdgcn_sched_barrier(0);
        __builtin_amdgcn_s_barrier();                   // all waves done reading buf
        __builtin_amdgcn_sched_barrier(0);
        // ---- stage kt+2 into this (now-drained) buffer; under MFMA ks1 ----
        if (kt + 2 < NT) { STAGE_A(buf, kt + 2); STAGE_B(buf, kt + 2); }
        __builtin_amdgcn_sched_barrier(0);
        __builtin_amdgcn_s_setprio(1);
        #pragma unroll
        for (int i = 0; i < 4; ++i)
            #pragma unroll
            for (int j = 0; j < 4; ++j)
                acc[i][j] = __builtin_amdgcn_mfma_f32_16x16x32_bf16(a[i], b[j], acc[i][j], 0, 0, 0);
        __builtin_amdgcn_s_setprio(0);
        if (kt + 2 < NT)      { asm volatile("s_waitcnt vmcnt(4)" ::: "memory"); }
        else if (kt + 1 < NT) { asm volatile("s_waitcnt vmcnt(0)" ::: "memory"); }
        __builtin_amdgcn_s_barrier();
        __builtin_amdgcn_sched_barrier(0);
    }
#undef STAGE_A
#undef STAGE_B

    // ---- epilogue: fp8 pack through LDS (As, 64 KB), coalesced store ----
    unsigned char* cbuf = (unsigned char*)&As[0][0][0];
    #pragma unroll
    for (int i = 0; i < 4; ++i)
        #pragma unroll
        for (int j = 0; j < 4; ++j) {
            int colL = wc * 64 + j * 16 + m15;
            #pragma unroll
            for (int reg = 0; reg < 4; ++reg) {
                int rowL = wr * 64 + i * 16 + q * 4 + reg;
                unsigned int pk = __builtin_amdgcn_cvt_pk_fp8_f32(
                    acc[i][j][reg], acc[i][j][reg], 0, false);
                cbuf[rowL * 256 + colL] = (unsigned char)(pk & 0xFF);
            }
        }
    __syncthreads();
    {
        int rowL = tid >> 2, colL = (tid & 3) * 64;
        const uint4* src = (const uint4*)&cbuf[rowL * 256 + colL];
        uint4* dst = (uint4*)(Z + (size_t)(rowBase + rowL) * DF + colBase + colL);
        #pragma unroll
        for (int x = 0; x < 4; ++x) dst[x] = src[x];
    }

    // ---- el/er fuse: per-row dot with al/ar, reduce over 16 col-lanes ----
    float alv[4], arv[4];
    #pragma unroll
    for (int j = 0; j < 4; ++j) {
        int col = colBase + wc * 64 + j * 16 + m15;
        alv[j] = al[r * DF + col];
        arv[j] = ar[r * DF + col];
    }
    float pe[4][4], pr[4][4];
    #pragma unroll
    for (int i = 0; i < 4; ++i)
        #pragma unroll
        for (int reg = 0; reg < 4; ++reg) {
            float se = 0.f, sr = 0.f;
            #pragma unroll
            for (int j = 0; j < 4; ++j) {
                se += acc[i][j][reg] * alv[j];
                sr += acc[i][j][reg] * arv[j];
            }
            pe[i][reg] = se; pr[i][reg] = sr;
        }
    #pragma unroll
    for (int off = 1; off < 16; off <<= 1)
        #pragma unroll
        for (int i = 0; i < 4; ++i)
            #pragma unroll
            for (int reg = 0; reg < 4; ++reg) {
                pe[i][reg] += __shfl_xor(pe[i][reg], off);
                pr[i][reg] += __shfl_xor(pr[i][reg], off);
            }
    float* eP = (float*)&Bs[0][0][0];                   // [2 heads][256 rows][2 strips]
    float* rP = eP + 1024;
    if (m15 == 0) {
        int hh = wc >> 1, strip = wc & 1;
        #pragma unroll
        for (int i = 0; i < 4; ++i)
            #pragma unroll
            for (int reg = 0; reg < 4; ++reg) {
                int rowL = wr * 64 + i * 16 + q * 4 + reg;
                eP[(hh * 256 + rowL) * 2 + strip] = pe[i][reg];
                rP[(hh * 256 + rowL) * 2 + strip] = pr[i][reg];
            }
    }
    __syncthreads();
    if (tid < 512) {
        int rowL = tid & 255, hh = tid >> 8;
        int head = (colBase >> 7) + hh;
        size_t idx = ((size_t)r * NN + rowBase + rowL) * NHD + head;
        el[idx] = eP[(hh * 256 + rowL) * 2] + eP[(hh * 256 + rowL) * 2 + 1];
        er[idx] = rP[(hh * 256 + rowL) * 2] + rP[(hh * 256 + rowL) * 2 + 1];
    }
}

// ---------------- bf16 MFMA GEMM: C[r] = A @ Bt[r]^T (+bias, opt relu) ------
// 128^2 tile, kept for KV projection and the split-K classifier GEMM.
template <typename OutT, bool RELU, bool FUSE, bool SPLITK = false>
__global__ __launch_bounds__(256) void mfma_gemm(
    const __hip_bfloat16* __restrict__ A,
    const __hip_bfloat16* __restrict__ BtAll,
    const float* __restrict__ bias, int biasStride,
    OutT* __restrict__ Call, int M, int N, int K, int lda,
    const float* __restrict__ al, const float* __restrict__ ar,
    float* __restrict__ el, float* __restrict__ er)
{
    int r = blockIdx.z;
    const __hip_bfloat16* Bt;
    int koff;
    if (SPLITK) { Bt = BtAll;                         koff = r * K; }
    else        { Bt = BtAll + (size_t)r * N * lda;   koff = 0; }
    OutT* C = Call + (size_t)r * M * N;
    const int rowBase = blockIdx.y * 128;
    const int colBase = blockIdx.x * 128;
    __shared__ __hip_bfloat16 As[128 * 64];
    __shared__ __hip_bfloat16 Bs[128 * 64];
    const int tid = threadIdx.x;
    const int w = tid >> 6, l = tid & 63;
    const int wr = w >> 1, wc = w & 1;
    const int m15 = l & 15, q = l >> 4;
    const int sRow = tid >> 3;                          // 0..31 (call adds 32*c)
    const int sChk = tid & 7;
    const __hip_bfloat16* Ag = A + (size_t)(rowBase + sRow) * lda + koff + sChk * 8;
    const __hip_bfloat16* Bg = Bt + (size_t)(colBase + sRow) * lda + koff + sChk * 8;
    __hip_bfloat16* Asl = As + tid * 8;
    __hip_bfloat16* Bsl = Bs + tid * 8;
    const int swr = m15 & 7;                            // read-side swizzle

    f32x4 acc[4][4];
    #pragma unroll
    for (int i = 0; i < 4; ++i)
        #pragma unroll
        for (int j = 0; j < 4; ++j) acc[i][j] = (f32x4){0.f, 0.f, 0.f, 0.f};

    for (int k0 = 0; k0 < K; k0 += 64) {
        #pragma unroll
        for (int c = 0; c < 4; ++c) {
            load_lds16(Ag + (size_t)c * 32 * lda + k0, Asl + c * 2048);
            load_lds16(Bg + (size_t)c * 32 * lda + k0, Bsl + c * 2048);
        }
        __syncthreads();
        #pragma unroll
        for (int g = 0; g < 2; ++g) {
            bf16x8 a[4], b[4];
            #pragma unroll
            for (int i = 0; i < 4; ++i)
                a[i] = *(const bf16x8*)&As[(wr * 64 + i * 16 + m15) * 64 + ((g * 4 + q) ^ swr) * 8];
            #pragma unroll
            for (int j = 0; j < 4; ++j)
                b[j] = *(const bf16x8*)&Bs[(wc * 64 + j * 16 + m15) * 64 + ((g * 4 + q) ^ swr) * 8];
            #pragma unroll
            for (int i = 0; i < 4; ++i)
                #pragma unroll
                for (int j = 0; j < 4; ++j)
                    acc[i][j] = __builtin_amdgcn_mfma_f32_16x16x32_bf16(a[i], b[j], acc[i][j], 0, 0, 0);
        }
        __syncthreads();
    }

    if constexpr (sizeof(OutT) == 1) {
        unsigned char* cbuf = (unsigned char*)As;
        #pragma unroll
        for (int i = 0; i < 4; ++i)
            #pragma unroll
            for (int j = 0; j < 4; ++j) {
                int colL = wc * 64 + j * 16 + m15;
                #pragma unroll
                for (int reg = 0; reg < 4; ++reg) {
                    int rowL = wr * 64 + i * 16 + q * 4 + reg;
                    unsigned int pk = __builtin_amdgcn_cvt_pk_fp8_f32(
                        acc[i][j][reg], acc[i][j][reg], 0, false);
                    cbuf[rowL * 128 + colL] = (unsigned char)(pk & 0xFF);
                }
            }
        __syncthreads();
        int rowL = tid >> 1, colL = (tid & 1) * 64;
        const uint4* src = (const uint4*)&cbuf[rowL * 128 + colL];
        uint4* dst = (uint4*)((unsigned char*)C + (size_t)(rowBase + rowL) * N
                              + colBase + colL);
        #pragma unroll
        for (int x = 0; x < 4; ++x) dst[x] = src[x];
    } else {
        #pragma unroll
        for (int i = 0; i < 4; ++i) {
            #pragma unroll
            for (int j = 0; j < 4; ++j) {
                int col = colBase + wc * 64 + j * 16 + m15;
                float bv = bias ? bias[r * biasStride + col] : 0.f;
                #pragma unroll
                for (int reg = 0; reg < 4; ++reg) {
                    int row = rowBase + wr * 64 + i * 16 + q * 4 + reg;
                    float v = acc[i][j][reg] + bv;
                    if (RELU) v = fmaxf(v, 0.f);
                    storeOut(&C[(size_t)row * N + col], v);
                }
            }
        }
    }

    if (FUSE) {
        float alv[4], arv[4];
        #pragma unroll
        for (int j = 0; j < 4; ++j) {
            int col = colBase + wc * 64 + j * 16 + m15;
            alv[j] = al[r * DF + col];
            arv[j] = ar[r * DF + col];
        }
        float pe[4][4], pr[4][4];
        #pragma unroll
        for (int i = 0; i < 4; ++i)
            #pragma unroll
            for (int reg = 0; reg < 4; ++reg) {
                float se = 0.f, sr = 0.f;
                #pragma unroll
                for (int j = 0; j < 4; ++j) {
                    se += acc[i][j][reg] * alv[j];
                    sr += acc[i][j][reg] * arv[j];
                }
                pe[i][reg] = se; pr[i][reg] = sr;
            }
        #pragma unroll
        for (int off = 1; off < 16; off <<= 1)
            #pragma unroll
            for (int i = 0; i < 4; ++i)
                #pragma unroll
                for (int reg = 0; reg < 4; ++reg) {
                    pe[i][reg] += __shfl_xor(pe[i][reg], off);
                    pr[i][reg] += __shfl_xor(pr[i][reg], off);
                }
        float* eP = (float*)Bs;
        float* rP = eP + 256;
        if (m15 == 0) {
            #pragma unroll
            for (int i = 0; i < 4; ++i)
                #pragma unroll
                for (int reg = 0; reg < 4; ++reg) {
                    int rowL = wr * 64 + i * 16 + q * 4 + reg;
                    eP[rowL * 2 + wc] = pe[i][reg];
                    rP[rowL * 2 + wc] = pr[i][reg];
                }
        }
        __syncthreads();
        if (tid < 128) {
            int head = colBase >> 7;
            size_t idx = ((size_t)r * NN + rowBase + tid) * NHD + head;
            el[idx] = eP[tid * 2] + eP[tid * 2 + 1];
            er[idx] = rP[tid * 2] + rP[tid * 2 + 1];
        }
    }
}

// ---------------- fp32 VALU GEMM for tiny M (q, ctx projections) ------------
template <typename OutT>
__global__ __launch_bounds__(256) void gemm_kernel(
    const float* __restrict__ A, const float* __restrict__ Bm,
    const float* __restrict__ bias, OutT* __restrict__ C,
    int M, int K, int Nn)
{
    int r = blockIdx.z;
    const float* B = Bm + (size_t)r * K * Nn;
    OutT* Cr = C + (size_t)r * M * Nn;
    int rowBase = blockIdx.y * 64;
    int colBase = blockIdx.x * 64;
    __shared__ float As[64][17];
    __shared__ float Bs[16][64];
    int tid = threadIdx.x;
    int tx = tid % 16, ty = tid / 16;
    float acc[4][4] = {};
    int aRow = tid / 4, aK4 = (tid % 4) * 4;
    int bK = tid / 16, bN4 = (tid % 16) * 4;
    for (int k0 = 0; k0 < K; k0 += 16) {
        int gRow = rowBase + aRow;
        float4 av = make_float4(0.f, 0.f, 0.f, 0.f);
        if (gRow < M) av = *(const float4*)(A + (size_t)gRow * K + k0 + aK4);
        As[aRow][aK4 + 0] = av.x; As[aRow][aK4 + 1] = av.y;
        As[aRow][aK4 + 2] = av.z; As[aRow][aK4 + 3] = av.w;
        float4 bv = *(const float4*)(B + (size_t)(k0 + bK) * Nn + colBase + bN4);
        *(float4*)&Bs[bK][bN4] = bv;
        __syncthreads();
        #pragma unroll
        for (int k = 0; k < 16; ++k) {
            float a[4], b[4];
            #pragma unroll
            for (int i = 0; i < 4; ++i) a[i] = As[ty * 4 + i][k];
            #pragma unroll
            for (int j = 0; j < 4; ++j) b[j] = Bs[k][tx * 4 + j];
            #pragma unroll
            for (int i = 0; i < 4; ++i)
                #pragma unroll
                for (int j = 0; j < 4; ++j) acc[i][j] += a[i] * b[j];
        }
        __syncthreads();
    }
    #pragma unroll
    for (int i = 0; i < 4; ++i) {
        int gRow = rowBase + ty * 4 + i;
        if (gRow >= M) continue;
        #pragma unroll
        for (int j = 0; j < 4; ++j) {
            int gCol = colBase + tx * 4 + j;
            float v = acc[i][j];
            if (bias) v += bias[gCol];
            storeOut(&Cr[(size_t)gRow * Nn + gCol], v);
        }
    }
}

// ---------------- per-(rel,node): den + alpha, pack into combined CSR -------
__global__ __launch_bounds__(256) void alpha_kernel(
    const float* __restrict__ el, const float* __restrict__ er,
    const int* __restrict__ rowptr, const int* __restrict__ rowptr2,
    const int* __restrict__ croff, const int* __restrict__ srcCSR,
    const int* __restrict__ eidCSR,
    float* __restrict__ alphaPk, int* __restrict__ srcPk,
    float* __restrict__ attn, float* __restrict__ imp)
{
    int t = blockIdx.x * 256 + threadIdx.x;             // < NREL*NN
    int r = t / NN, n = t % NN;
    int start = rowptr[r * (NN + 1) + n];
    int d = rowptr[r * (NN + 1) + n + 1] - start;
    if (d == 0) return;
    int pbase = rowptr2[n] + croff[r * NN + n];
    float4 er4 = *(const float4*)&er[((size_t)r * NN + n) * NHD];
    float4 den = make_float4(0.f, 0.f, 0.f, 0.f);
    for (int j = 0; j < d; ++j) {
        int s = srcCSR[r * NE + start + j];
        float4 el4 = *(const float4*)&el[((size_t)r * NN + s) * NHD];
        float v0 = el4.x + er4.x; v0 = v0 > 0.f ? v0 : 0.2f * v0;
        float v1 = el4.y + er4.y; v1 = v1 > 0.f ? v1 : 0.2f * v1;
        float v2 = el4.z + er4.z; v2 = v2 > 0.f ? v2 : 0.2f * v2;
        float v3 = el4.w + er4.w; v3 = v3 > 0.f ? v3 : 0.2f * v3;
        float4 e4 = make_float4(__expf(v0), __expf(v1), __expf(v2), __expf(v3));
        den.x += e4.x; den.y += e4.y; den.z += e4.z; den.w += e4.w;
        *(float4*)&alphaPk[(size_t)(pbase + j) * 4] = e4;
        srcPk[pbase + j] = r * NN + s;                  // direct Z-row index
    }
    float4 inv = make_float4(1.f / den.x, 1.f / den.y, 1.f / den.z, 1.f / den.w);
    float impLoc = 0.f;
    for (int j = 0; j < d; ++j) {
        float4 a4 = *(const float4*)&alphaPk[(size_t)(pbase + j) * 4];
        a4.x *= inv.x; a4.y *= inv.y; a4.z *= inv.z; a4.w *= inv.w;
        *(float4*)&alphaPk[(size_t)(pbase + j) * 4] = a4;
        if (attn) {
            float a = 0.25f * (a4.x + a4.y + a4.z + a4.w);
            attn[r * NE + eidCSR[r * NE + start + j]] = a;
            impLoc += a;
        }
    }
    if (attn) atomicAdd(&imp[n], impLoc);
}

// ---------------- combined aggregation: block per node, 4 waves -------------
// Gather pipeline deepened 4 -> 8 rows in flight per wave (32 edges per
// block-iteration): if the Z gathers are latency-bound this halves exposed
// latency; if BW-bound it is neutral. Edge->wave assignment changes are fp32
// reassociation only (every edge counted exactly once).
__global__ __launch_bounds__(256) void aggc_kernel(
    const unsigned char* __restrict__ Z,
    const int* __restrict__ rowptr2, const int* __restrict__ srcPk,
    const float* __restrict__ alphaPk, const float* __restrict__ bsum,
    const float* __restrict__ hin, float* __restrict__ hout,
    __hip_bfloat16* __restrict__ hout_bf, int applyElu)
{
    int n = blockIdx.x;
    int w = threadIdx.x >> 6, lane = threadIdx.x & 63;
    int h = lane >> 4;
    int base = rowptr2[n];
    int deg = rowptr2[n + 1] - base;
    float acc[8] = {};
    if (deg > 0) {
        int i = w * 8;
        int zz[8]; float aa[8];
        #pragma unroll
        for (int j = 0; j < 8; ++j) {
            int idx = i + j; int cidx = idx < deg ? idx : deg - 1;
            zz[j] = srcPk[base + cidx];
            aa[j] = (idx < deg) ? alphaPk[(size_t)(base + cidx) * 4 + h] : 0.f;
        }
        while (i < deg) {
            int cz[8]; float ca[8];
            #pragma unroll
            for (int j = 0; j < 8; ++j) { cz[j] = zz[j]; ca[j] = aa[j]; }
            int ni = i + 32;
            #pragma unroll
            for (int j = 0; j < 8; ++j) {
                int idx = ni + j; int cidx = idx < deg ? idx : deg - 1;
                zz[j] = srcPk[base + cidx];
                aa[j] = (idx < deg) ? alphaPk[(size_t)(base + cidx) * 4 + h] : 0.f;
            }
            uint2 raw[8];
            #pragma unroll
            for (int j = 0; j < 8; ++j)
                raw[j] = *(const uint2*)&Z[(size_t)cz[j] * DF + lane * 8];
            #pragma unroll
            for (int j = 0; j < 8; ++j) {
                f32x2 f01 = __builtin_amdgcn_cvt_pk_f32_fp8((int)raw[j].x, false);
                f32x2 f23 = __builtin_amdgcn_cvt_pk_f32_fp8((int)raw[j].x, true);
                f32x2 f45 = __builtin_amdgcn_cvt_pk_f32_fp8((int)raw[j].y, false);
                f32x2 f67 = __builtin_amdgcn_cvt_pk_f32_fp8((int)raw[j].y, true);
                acc[0] += ca[j] * f01.x; acc[1] += ca[j] * f01.y;
                acc[2] += ca[j] * f23.x; acc[3] += ca[j] * f23.y;
                acc[4] += ca[j] * f45.x; acc[5] += ca[j] * f45.y;
                acc[6] += ca[j] * f67.x; acc[7] += ca[j] * f67.y;
            }
            i = ni;
        }
    }
    __shared__ float red[4][DF];
    #pragma unroll
    for (int j = 0; j < 8; ++j) red[w][lane * 8 + j] = acc[j];
    __syncthreads();
    const float invR = 1.0f / NREL;
    const int sw = (n & 7) << 3;
    int f = threadIdx.x;
    #pragma unroll
    for (int rep = 0; rep < 2; ++rep, f += 256) {
        float v = red[0][f] + red[1][f] + red[2][f] + red[3][f];
        v = (v + bsum[f]) * invR + hin[(size_t)n * DF + f];
        if (applyElu) v = v > 0.f ? v : expm1f(v);
        hout[(size_t)n * DF + f] = v;
        hout_bf[(size_t)n * DF + (f ^ sw)] = __float2bfloat16(v);   // swizzled
    }
}

// ---------------- MHA: scores, then fused softmax+context -------------------
__global__ __launch_bounds__(256) void mha_scores(
    const float* __restrict__ q, const float* __restrict__ k,
    float* __restrict__ scores)
{
    int b = blockIdx.x;
    int w = threadIdx.x >> 6, lane = threadIdx.x & 63;
    int s = blockIdx.y * 4 + w;
    const float4* qp = (const float4*)&q[(size_t)b * DF + lane * 8];
    const float4* kp = (const float4*)&k[((size_t)(b * NS + s)) * DF + lane * 8];
    float4 q0 = qp[0], q1 = qp[1];
    float4 k0 = kp[0], k1 = kp[1];
    float p = q0.x * k0.x + q0.y * k0.y + q0.z * k0.z + q0.w * k0.w
            + q1.x * k1.x + q1.y * k1.y + q1.z * k1.z + q1.w * k1.w;
    #pragma unroll
    for (int off = 1; off < 16; off <<= 1) p += __shfl_xor(p, off);
    if ((lane & 15) == 0) {
        int h = lane >> 4;
        scores[((size_t)(b * NHD + h)) * NS + s] = p * 0.08838834764831845f;
    }
}

// softmax folded in (was a separate mha_soft launch)
__global__ __launch_bounds__(256) void mha_ctx(
    const float* __restrict__ scores, const float* __restrict__ v,
    float* __restrict__ ctx)
{
    int b = blockIdx.x, h = blockIdx.y;
    int t = threadIdx.x;
    int lane = t & 63, w = t >> 6;
    __shared__ float a_s[NS];
    __shared__ float wred[8];
    float sv = scores[((size_t)(b * NHD + h)) * NS + t];
    float mx = sv;
    #pragma unroll
    for (int off = 1; off < 64; off <<= 1) mx = fmaxf(mx, __shfl_xor(mx, off));
    if (lane == 0) wred[w] = mx;
    __syncthreads();
    mx = fmaxf(fmaxf(wred[0], wred[1]), fmaxf(wred[2], wred[3]));
    float e = __expf(sv - mx);
    float sum = e;
    #pragma unroll
    for (int off = 1; off < 64; off <<= 1) sum += __shfl_xor(sum, off);
    if (lane == 0) wred[4 + w] = sum;
    __syncthreads();
    sum = wred[4] + wred[5] + wred[6] + wred[7];
    a_s[t] = e * (1.0f / sum);
    __syncthreads();
    int d = t & 127, half = t >> 7;
    float acc = 0.f;
    const float* vp = &v[((size_t)(b * NS + half * 128)) * DF + h * DHH + d];
    #pragma unroll 4
    for (int i = 0; i < 128; ++i)
        acc += a_s[half * 128 + i] * vp[(size_t)i * DF];
    __shared__ float red[256];
    red[t] = acc;
    __syncthreads();
    if (t < 128) ctx[(size_t)b * DF + h * DHH + t] = red[t] + red[t + 128];
}

// ---------------- classifier: build combined bf16 [NN, 2*DF] (swizzled) -----
__global__ __launch_bounds__(256) void combined_kernel(
    const float* __restrict__ feats, const float* __restrict__ imp,
    const float* __restrict__ abuf, __hip_bfloat16* __restrict__ comb)
{
    int n = blockIdx.x;
    int t = threadIdx.x;
    int b = n >> 8;
    float im = imp[n];
    const int sw = (n & 7) << 3;
    #pragma unroll
    for (int rep = 0; rep < 4; ++rep) {
        int f = t + rep * 256;
        float v = (f < DF) ? feats[(size_t)n * DF + f] * im
                           : abuf[(size_t)b * DF + (f - DF)];
        comb[(size_t)n * (2 * DF) + (f ^ sw)] = __float2bfloat16(v);
    }
}

// sum 4 split-K partials + bias + relu, then x Wn2
// 4 threads per node (tq = t&3, 32 kk each) -> 64 blocks, shfl-reduced
// (was 16 blocks = 6% CU coverage).
__global__ __launch_bounds__(256) void cls2_kernel(
    const float* __restrict__ hidden4, const float* __restrict__ bn1,
    const float* __restrict__ Wn2, const float* __restrict__ bn2,
    float* __restrict__ out)
{
    __shared__ float w2[256];
    __shared__ float b1s[128];
    int t = threadIdx.x;
    w2[t] = Wn2[t];
    if (t < 128) b1s[t] = bn1[t];
    __syncthreads();
    int n = blockIdx.x * 64 + (t >> 2);
    int tq = t & 3;
    const float* hp = &hidden4[(size_t)n * 128];
    const size_t ps = (size_t)NN * 128;
    float p0 = 0.f, p1 = 0.f;
    int k0 = tq * 32;
    #pragma unroll 4
    for (int kk = k0; kk < k0 + 32; ++kk) {
        float hv = hp[kk] + hp[ps + kk] + hp[2 * ps + kk] + hp[3 * ps + kk] + b1s[kk];
        hv = fmaxf(hv, 0.f);
        p0 += hv * w2[kk * 2 + 0];
        p1 += hv * w2[kk * 2 + 1];
    }
    p0 += __shfl_xor(p0, 1); p0 += __shfl_xor(p0, 2);
    p1 += __shfl_xor(p1, 1); p1 += __shfl_xor(p1, 2);
    if (tq == 0) {
        out[n * 2 + 0] = p0 + bn2[0];
        out[n * 2 + 1] = p1 + bn2[1];
    }
}

extern "C" void kernel_launch(void* const* d_in, const int* in_sizes, int n_in,
                              void* d_out, int out_size, void* d_ws, size_t ws_size,
                              hipStream_t stream) {
    const float* feat = (const float*)d_in[0];
    const float* hyp  = (const float*)d_in[1];
    const int*   esrc = (const int*)d_in[2];
    const int*   edst = (const int*)d_in[3];
    const float* W1   = (const float*)d_in[4];
    const float* al1  = (const float*)d_in[5];
    const float* ar1  = (const float*)d_in[6];
    const float* b1   = (const float*)d_in[7];
    const float* W2   = (const float*)d_in[8];
    const float* al2  = (const float*)d_in[9];
    const float* ar2  = (const float*)d_in[10];
    const float* b2   = (const float*)d_in[11];
    const float* Wq = (const float*)d_in[12]; const float* bq = (const float*)d_in[13];
    const float* Wk = (const float*)d_in[14]; const float* bk = (const float*)d_in[15];
    const float* Wv = (const float*)d_in[16]; const float* bv = (const float*)d_in[17];
    const float* Wo = (const float*)d_in[18]; const float* bo = (const float*)d_in[19];
    const float* Wn1 = (const float*)d_in[20]; const float* bn1 = (const float*)d_in[21];
    const float* Wn2 = (const float*)d_in[22]; const float* bn2 = (const float*)d_in[23];

    char* ws = (char*)d_ws;
    size_t off = 0;
    auto alloc = [&](size_t bytes) -> void* {
        void* p = ws + off;
        off += (bytes + 255) & ~(size_t)255;
        return p;
    };
    unsigned char* Z = (unsigned char*)alloc((size_t)NREL * NN * DF);     // fp8
    float* el     = (float*)alloc((size_t)NREL * NN * NHD * 4);
    float* er     = (float*)alloc((size_t)NREL * NN * NHD * 4);
    int* rowptr   = (int*)alloc((size_t)NREL * (NN + 1) * 4);
    int* rowptr2  = (int*)alloc((size_t)(NN + 1) * 4);
    int* woff     = (int*)alloc((size_t)NREL * NN * 4);
    int* srcCSR   = (int*)alloc((size_t)NREL * NE * 4);
    int* eidCSR   = (int*)alloc((size_t)NREL * NE * 4);
    int* cnt      = (int*)alloc((size_t)NREL * NN * 4);
    int* croff    = (int*)alloc((size_t)NREL * NN * 4);
    int* srcPk    = (int*)alloc((size_t)NREL * NE * 4);
    float* alphaPk= (float*)alloc((size_t)NREL * NE * NHD * 4);
    float* bsum1  = (float*)alloc((size_t)DF * 4);
    float* bsum2  = (float*)alloc((size_t)DF * 4);
    float* bkv    = (float*)alloc((size_t)2 * DF * 4);
    float* h1     = (float*)alloc((size_t)NN * DF * 4);
    float* feats  = (float*)alloc((size_t)NN * DF * 4);
    float* imp    = (float*)alloc((size_t)NN * 4);
    float* kvbuf  = (float*)alloc((size_t)2 * NN * DF * 4);
    float* qbuf   = (float*)alloc((size_t)NB * DF * 4);
    float* ctxb   = (float*)alloc((size_t)NB * DF * 4);
    float* abuf   = (float*)alloc((size_t)NB * DF * 4);
    float* scoresb= (float*)alloc((size_t)NB * NHD * NS * 4);
    float* hidden4= (float*)alloc((size_t)4 * NN * 128 * 4);
    __hip_bfloat16* featbf  = (__hip_bfloat16*)alloc((size_t)NN * DF * 2);
    __hip_bfloat16* h1bf    = (__hip_bfloat16*)alloc((size_t)NN * DF * 2);
    __hip_bfloat16* featsbf = (__hip_bfloat16*)alloc((size_t)NN * DF * 2);
    __hip_bfloat16* combbf  = (__hip_bfloat16*)alloc((size_t)NN * 2 * DF * 2);
    __hip_bfloat16* Wt1 = (__hip_bfloat16*)alloc((size_t)NREL * DF * DF * 2);
    __hip_bfloat16* Wt2 = (__hip_bfloat16*)alloc((size_t)NREL * DF * DF * 2);
    __hip_bfloat16* WtKV = (__hip_bfloat16*)alloc((size_t)2 * DF * DF * 2);
    __hip_bfloat16* Wn1t = (__hip_bfloat16*)alloc((size_t)(2 * DF) * 128 * 2);
    if (off > ws_size) return;

    float* logits = (float*)d_out;
    float* attn   = (float*)d_out + (size_t)NN * 2;
    float* kbuf = kvbuf;
    float* vbuf = kvbuf + (size_t)NN * DF;

    // ---- prep: zero cnt/imp, cast+swizzle feat, bias sums, bkv concat ----
    prep_kernel<<<1026 + NREL * NN / 256, 256, 0, stream>>>(
        feat, (unsigned short*)featbf, b1, b2, bk, bv, bsum1, bsum2, bkv, cnt, imp);

    // ---- CSR build (shared by both layers) ----
    count_kernel<<<NREL * NE / 256, 256, 0, stream>>>(edst, cnt);
    scan_kernel<<<NREL + 1, 1024, 0, stream>>>(cnt, rowptr, woff, rowptr2, croff);
    fill_kernel<<<NREL * NE / 256, 256, 0, stream>>>(edst, esrc, woff, srcCSR, eidCSR);

    // ---- weight transposes (bf16, K-chunk swizzled); W1+W2+Wk+Wv merged ----
    transw2_kernel<<<dim3(DF / 32, DF / 32, 2 * NREL + 2), 256, 0, stream>>>(
        W1, W2, Wk, Wv, Wt1, Wt2, WtKV);
    transw_kernel<<<dim3(2 * DF / 32, 128 / 32, 1), 256, 0, stream>>>(Wn1, Wn1t, 2 * DF, 128);

    // ---- layer 1: 256^2 16-wave Z-GEMM with fp8 out + el/er fuse ----
    zgemm16<<<dim3(DF / 256, NN / 256, NREL), 1024, 0, stream>>>(
        featbf, Wt1, Z, al1, ar1, el, er);
    alpha_kernel<<<NREL * NN / 256, 256, 0, stream>>>(
        el, er, rowptr, rowptr2, croff, srcCSR, eidCSR, alphaPk, srcPk, attn, imp);
    aggc_kernel<<<NN, 256, 0, stream>>>(Z, rowptr2, srcPk, alphaPk, bsum1,
                                        feat, h1, h1bf, 1);

    // ---- layer 2 ----
    zgemm16<<<dim3(DF / 256, NN / 256, NREL), 1024, 0, stream>>>(
        h1bf, Wt2, Z, al2, ar2, el, er);
    alpha_kernel<<<NREL * NN / 256, 256, 0, stream>>>(
        el, er, rowptr, rowptr2, croff, srcCSR, eidCSR, alphaPk, srcPk, nullptr, nullptr);
    aggc_kernel<<<NN, 256, 0, stream>>>(Z, rowptr2, srcPk, alphaPk, bsum2,
                                        h1, feats, featsbf, 0);

    // ---- MHA (KV MFMA + 4 small kernels) ----
    mfma_gemm<float, false, false><<<dim3(DF / 128, NN / 128, 2), 256, 0, stream>>>(
        featsbf, WtKV, bkv, DF, kvbuf, NN, DF, DF, DF, nullptr, nullptr, nullptr, nullptr);
    gemm_kernel<float><<<dim3(DF / 64, 1, 1), 256, 0, stream>>>(
        hyp, Wq, bq, qbuf, NB, DF, DF);
    mha_scores<<<dim3(NB, NS / 4), 256, 0, stream>>>(qbuf, kbuf, scoresb);
    mha_ctx<<<dim3(NB, NHD), 256, 0, stream>>>(scoresb, vbuf, ctxb);
    gemm_kernel<float><<<dim3(DF / 64, 1, 1), 256, 0, stream>>>(
        ctxb, Wo, bo, abuf, NB, DF, DF);

    // ---- classifier (split-K=4, partials summed in cls2) ----
    combined_kernel<<<NN, 256, 0, stream>>>(feats, imp, abuf, combbf);
    mfma_gemm<float, false, false, true><<<dim3(1, NN / 128, 4), 256, 0, stream>>>(
        combbf, Wn1t, nullptr, 0, hidden4, NN, 128, 256, 2 * DF,
        nullptr, nullptr, nullptr, nullptr);
    cls2_kernel<<<NN / 64, 256, 0, stream>>>(hidden4, bn1, Wn2, bn2, logits);
}